// Round 9
// baseline (1204.515 us; speedup 1.0000x reference)
//
#include <hip/hip_runtime.h>
#include <hip/hip_bf16.h>

// NestedAttention: B=16,N=1024,D=1024,E=4,H=16,hd=64
// bf16 MFMA pipeline with fp32 accumulate.
// R9: 256^2 tile (keeps FETCH ~47MB; R8's 128^2 exploded it to 206MB) but
// SINGLE-buffered 64KB LDS -> launch_bounds(512,4) = 2 blocks/CU, so the
// per-tile vmcnt(0) drain is hidden by the co-resident block (m97/m114
// mechanism). Per-batch expert sort; pipeline in permuted token space;
// nested-K QKV; masked-block-skip proj; T2 swizzle everywhere.

typedef __bf16 bf16_t;
typedef __bf16 bf16x8 __attribute__((ext_vector_type(8)));
typedef __bf16 bf16x4 __attribute__((ext_vector_type(4)));
typedef float f32x4 __attribute__((ext_vector_type(4)));
typedef float f32x16 __attribute__((ext_vector_type(16)));
typedef int i32x4 __attribute__((ext_vector_type(4)));

typedef __attribute__((address_space(1))) void gvoid;
typedef __attribute__((address_space(3))) void lvoid;

#define MFMA16(a, b, c) __builtin_amdgcn_mfma_f32_16x16x32_bf16((a), (b), (c), 0, 0, 0)
#define MFMA32(a, b, c) __builtin_amdgcn_mfma_f32_32x32x16_bf16((a), (b), (c), 0, 0, 0)
#define GLOAD_LDS16(gsrc, ldst) \
  __builtin_amdgcn_global_load_lds((gvoid*)(gsrc), (lvoid*)(ldst), 16, 0, 0)

// softmax scale 1/sqrt(64) folded with log2(e) into Q at QKV epilogue
#define QSCALE 0.18033688f

__device__ __forceinline__ unsigned cvtpk(float lo, float hi) {
  unsigned r;
  asm("v_cvt_pk_bf16_f32 %0, %1, %2" : "=v"(r) : "v"(lo), "v"(hi));
  return r;
}
__device__ __forceinline__ void pl32swap(unsigned& x, unsigned& y) {
  asm("v_permlane32_swap_b32 %0, %1" : "+v"(x), "+v"(y));
}

// ------------------------------------------------------------- sorting ----
// Per-batch counting sort (16 batches x 1024 tokens) into ascending-expert
// order. perm[b*1024+np] = original n; ems[b*1024+np] = expert. Bucket
// boundaries are deterministic (counts); within-bucket order is atomic-race
// dependent, but every output row depends only on its own token, so final
// outputs are bit-identical across replays.
__global__ __launch_bounds__(256) void sort_batch(
    const int* __restrict__ em, int* __restrict__ perm, int* __restrict__ ems) {
  __shared__ int cnt[4], base[4], cur[4];
  const int b = blockIdx.x, t = threadIdx.x;
  if (t < 4) cnt[t] = 0;
  __syncthreads();
  int e[4];
#pragma unroll
  for (int i = 0; i < 4; ++i) {
    e[i] = em[b * 1024 + t * 4 + i];
    atomicAdd(&cnt[e[i]], 1);
  }
  __syncthreads();
  if (t == 0) {
    base[0] = 0; base[1] = cnt[0];
    base[2] = cnt[0] + cnt[1]; base[3] = cnt[0] + cnt[1] + cnt[2];
    cur[0] = cur[1] = cur[2] = cur[3] = 0;
  }
  __syncthreads();
#pragma unroll
  for (int i = 0; i < 4; ++i) {
    const int pos = base[e[i]] + atomicAdd(&cur[e[i]], 1);
    perm[b * 1024 + pos] = t * 4 + i;
    ems[b * 1024 + pos] = e[i];
  }
}

// ---------------------------------------------------------------- prep ----
// gather token perm[np] of batch b -> permuted row np (coalesced 4KB row
// reads, contiguous writes), masked+converted to bf16.
__global__ __launch_bounds__(256) void prep_tokens(
    const float* __restrict__ x, const int* __restrict__ perm,
    const int* __restrict__ ems, bf16_t* __restrict__ xq) {
  const int prow = blockIdx.x;                // permuted row 0..16383
  const int orig = (prow & ~1023) + perm[prow];
  const int dt = 128 << ems[prow];            // token's nested dim
  const int d = threadIdx.x * 4;
  float4 v = ((const float4*)(x + (size_t)orig * 1024))[threadIdx.x];
  const bool keep = d < dt;                   // dt multiple of 128 -> uniform per 4
  bf16x4 o;
  o[0] = (bf16_t)(keep ? v.x : 0.f);
  o[1] = (bf16_t)(keep ? v.y : 0.f);
  o[2] = (bf16_t)(keep ? v.z : 0.f);
  o[3] = (bf16_t)(keep ? v.w : 0.f);
  *((bf16x4*)(xq + (size_t)prow * 1024 + d)) = o;
}

__global__ __launch_bounds__(256) void conv_w(
    const float* __restrict__ s, bf16_t* __restrict__ dvec) {
  const int i = blockIdx.x * 256 + threadIdx.x;  // grid sized exactly, no guard
  float4 v = ((const float4*)s)[i];
  bf16x4 o;
  o[0] = (bf16_t)v.x; o[1] = (bf16_t)v.y; o[2] = (bf16_t)v.z; o[3] = (bf16_t)v.w;
  ((bf16x4*)dvec)[i] = o;
}

// ---------------------------------------------------------------- GEMM ----
// C[m,f] = sum_k A[m,k] * Bw[f,k]  ("B^T" GEMM) over PERMUTED-space rows
// (contiguous; no gather). 256x256 tile, BK=64, 8 waves (2M x 4N),
// SINGLE-buffered 64KB LDS (2 blocks/CU; m97-style stage->drain->compute,
// drain hidden by co-resident block), T2 chunk-swizzled LDS (rule #21).
// EPI 0 (QKV): K-loop to the block's max nested dim (ascending experts ->
//   last row is max; zeros beyond a row's own dt keep straddle blocks
//   exact). Epilogue writes q(scaled)/k/vT at PERMUTED positions.
// EPI 1 (proj): full K; blocks with colbase >= dtmax write zeros (scattered
//   full 1KB rows) and exit; else per-row mask, scatter rows to orig pos.
template <int EPI>
__global__ __launch_bounds__(512, 4) void gemm256(
    const bf16_t* __restrict__ A, const bf16_t* __restrict__ Bw, int K,
    const int* __restrict__ perm, const int* __restrict__ ems,
    bf16_t* __restrict__ qo, bf16_t* __restrict__ ko, bf16_t* __restrict__ vto,
    float* __restrict__ yout, const float* __restrict__ bias) {
  __shared__ bf16_t lds[32768];  // A 32KB + B 32KB (chunk-swizzled), 1 buf
  const int tid = threadIdx.x;
  const int lane = tid & 63, w = tid >> 6;
  const int wm = w >> 2, wn = w & 3;
  const int g = lane >> 4, c16 = lane & 15;

  const int bid = blockIdx.x;
  const int rowbase = (bid & 63) * 256;   // row-blocks cycle fastest (balance)
  const int colbase = (bid >> 6) * 256;

  // block's max nested dim (ascending experts within batch; 256 | 1024 so a
  // block never straddles batches)
  const int dtmax = 128 << ems[rowbase + 255];

  if constexpr (EPI == 1) {
    if (colbase >= dtmax) {  // whole block masked -> write zero rows, done
      const float4 z = make_float4(0.f, 0.f, 0.f, 0.f);
#pragma unroll
      for (int i = 0; i < 32; ++i) {
        const int idx = i * 512 + tid;
        const int r = idx >> 6, c4 = idx & 63;
        const int orow = ((rowbase + r) & ~1023) + perm[rowbase + r];
        ((float4*)(yout + (size_t)orow * 1024 + colbase))[c4] = z;
      }
      return;
    }
  }

  const int NT = (EPI == 0) ? (dtmax >> 6) : (K >> 6);  // nested K for QKV

  // staging: thread stages 8x16B chunks/K-tile; linear LDS dest, inverse-
  // swizzled global source (chunk col = (tid&7) ^ (row&7); rule #21).
  const int trow = tid >> 3;
  const int scol = (((tid & 7) ^ (trow & 7)) << 3);
  const bf16_t* pa = A + (size_t)(rowbase + trow) * K + scol;
  const bf16_t* pb = Bw + (size_t)(colbase + trow) * K + scol;

#define STAGE(j, koff)                                            \
  GLOAD_LDS16(((j) < 4 ? pa + (size_t)((j) * 64) * K              \
                       : pb + (size_t)(((j) - 4) * 64) * K) +     \
                  (koff),                                         \
              lds + ((j) * 512 + tid) * 8)

  // swizzled fragment read: row R, k-chunk (kk*4+g), elem = R*64 + swz*8
#define LDFRAG(base, R, kk)            \
  (*(const bf16x8*)((base) + (size_t)(R) * 64 + \
                    (((((kk) << 2) + g) ^ (c16 & 7)) << 3)))

  f32x4 acc[8][4] = {};

  for (int t = 0; t < NT; ++t) {
    const int koff = t << 6;
    // stage this K-tile (single buffer); drain; publish. With 2 blocks/CU
    // the other block's MFMA phase covers this block's drain.
#pragma unroll
    for (int j = 0; j < 8; ++j) STAGE(j, koff);
    asm volatile("s_waitcnt vmcnt(0)" ::: "memory");
    __builtin_amdgcn_s_barrier();

    const bf16_t* Lb = lds;
    const bf16_t* LbB = lds + 16384;

    // quadrant compute, no intra-tile barriers: compiler interleaves
    // ds_read (counted lgkmcnt) with MFMA.
    bf16x8 af[4][2], af2[4][2], b0[2][2], b1[2][2];
#pragma unroll
    for (int mi = 0; mi < 4; ++mi)
#pragma unroll
      for (int kk = 0; kk < 2; ++kk)
        af[mi][kk] = LDFRAG(Lb, wm * 128 + mi * 16 + c16, kk);
#pragma unroll
    for (int ni = 0; ni < 2; ++ni)
#pragma unroll
      for (int kk = 0; kk < 2; ++kk)
        b0[ni][kk] = LDFRAG(LbB, wn * 64 + ni * 16 + c16, kk);
#pragma unroll
    for (int mi = 0; mi < 4; ++mi)
#pragma unroll
      for (int ni = 0; ni < 2; ++ni)
#pragma unroll
        for (int kk = 0; kk < 2; ++kk)
          acc[mi][ni] = MFMA16(af[mi][kk], b0[ni][kk], acc[mi][ni]);

#pragma unroll
    for (int ni = 0; ni < 2; ++ni)
#pragma unroll
      for (int kk = 0; kk < 2; ++kk)
        b1[ni][kk] = LDFRAG(LbB, wn * 64 + (ni + 2) * 16 + c16, kk);
#pragma unroll
    for (int mi = 0; mi < 4; ++mi)
#pragma unroll
      for (int ni = 0; ni < 2; ++ni)
#pragma unroll
        for (int kk = 0; kk < 2; ++kk)
          acc[mi][ni + 2] = MFMA16(af[mi][kk], b1[ni][kk], acc[mi][ni + 2]);

#pragma unroll
    for (int mi = 0; mi < 4; ++mi)
#pragma unroll
      for (int kk = 0; kk < 2; ++kk)
        af2[mi][kk] = LDFRAG(Lb, wm * 128 + (mi + 4) * 16 + c16, kk);
#pragma unroll
    for (int mi = 0; mi < 4; ++mi)
#pragma unroll
      for (int ni = 0; ni < 2; ++ni)
#pragma unroll
        for (int kk = 0; kk < 2; ++kk)
          acc[mi + 4][ni] = MFMA16(af2[mi][kk], b0[ni][kk], acc[mi + 4][ni]);

#pragma unroll
    for (int mi = 0; mi < 4; ++mi)
#pragma unroll
      for (int ni = 0; ni < 2; ++ni)
#pragma unroll
        for (int kk = 0; kk < 2; ++kk)
          acc[mi + 4][ni + 2] = MFMA16(af2[mi][kk], b1[ni][kk], acc[mi + 4][ni + 2]);

    // all waves done reading before next tile's STAGE overwrites LDS
    __builtin_amdgcn_s_barrier();
  }

  // C/D layout: col = lane&15, row = (lane>>4)*4 + reg  [m89/m91 verified]
  if constexpr (EPI == 0) {
    const int s = colbase >> 10;  // 0=q,1=k,2=v (uniform per block: 256|1024)
#pragma unroll
    for (int mi = 0; mi < 8; ++mi)
#pragma unroll
      for (int j = 0; j < 4; ++j) {
        const int row = rowbase + wm * 128 + mi * 16 + g * 4 + j;  // permuted
        const int bb = row >> 10, n = row & 1023;  // n = permuted position
#pragma unroll
        for (int ni = 0; ni < 4; ++ni) {
          const int col = colbase + wn * 64 + ni * 16 + c16;  // f
          const float v = acc[mi][ni][j];
          const int h = (col >> 6) & 15, e = col & 63;
          const size_t bh = (size_t)(bb * 16 + h);
          if (s == 0)
            qo[(bh * 1024 + n) * 64 + e] = (bf16_t)(v * QSCALE);
          else if (s == 1)
            ko[(bh * 1024 + n) * 64 + e] = (bf16_t)v;
          else
            vto[(bh * 64 + e) * 1024 + n] = (bf16_t)v;  // V transposed
        }
      }
  } else {
#pragma unroll
    for (int mi = 0; mi < 8; ++mi)
#pragma unroll
      for (int j = 0; j < 4; ++j) {
        const int row = rowbase + wm * 128 + mi * 16 + g * 4 + j;  // permuted
        const int dt = 128 << ems[row];
        const int orow = (row & ~1023) + perm[row];  // original token row
#pragma unroll
        for (int ni = 0; ni < 4; ++ni) {
          const int col = colbase + wn * 64 + ni * 16 + c16;
          const float v = acc[mi][ni][j] + bias[col];
          yout[(size_t)orow * 1024 + col] = (col < dt) ? v : 0.f;
        }
      }
  }
#undef STAGE
#undef LDFRAG
}

// ----------------------------------------------------------- attention ----
// Runs entirely in permuted token space (softmax over a batch's keys is
// permutation-invariant; each output row is its own query's result).
// 8 waves x 32 q-rows = 256 q rows / block. KVBLK=64 double-buffered in LDS
// (K row-major [64key][64d], V^T [64d][64key], both XOR-swizzled).
// Swapped QK^T: S = mfma32(Kfrag, Qfrag) -> lane holds P-row slice for
// q = lane&31 in registers; softmax fully in-register; P->bf16 via
// cvt_pk + permlane32_swap feeds PV's A operand directly.
__global__ __launch_bounds__(512, 2) void attn256(
    const bf16_t* __restrict__ Q, const bf16_t* __restrict__ Kb,
    const bf16_t* __restrict__ VT, bf16_t* __restrict__ X) {
  __shared__ bf16_t Klds[2][4096];
  __shared__ bf16_t Vlds[2][4096];
  const int tid = threadIdx.x;
  const int w = tid >> 6, lane = tid & 63;
  const int k32 = lane & 31, q5 = lane >> 5;
  const int bh = blockIdx.y;
  const int qbase = blockIdx.x * 256 + w * 32;

  const bf16_t* Qbh = Q + (size_t)bh * 65536;
  const bf16_t* Kbh = Kb + (size_t)bh * 65536;
  const bf16_t* Vbh = VT + (size_t)bh * 65536;

  const int trow = tid >> 3;
  const int tslot = (tid & 7) ^ (trow & 7);
  const bf16_t* kg = Kbh + (size_t)trow * 64 + tslot * 8;
  const bf16_t* vg = Vbh + (size_t)trow * 1024 + tslot * 8;

  bf16x8 qf[4];
#pragma unroll
  for (int kc = 0; kc < 4; ++kc)
    qf[kc] = *(const bf16x8*)(Qbh + (size_t)(qbase + k32) * 64 + kc * 16 + q5 * 8);
  asm volatile("" ::"v"(qf[0]), "v"(qf[1]), "v"(qf[2]), "v"(qf[3]));

  const int rbase = k32 * 128 + q5 * 16;
  const int rswz = (k32 & 7) << 4;

  f32x16 O0 = {}, O1 = {};
  float m = -3.0e38f, lsum = 0.f;

  GLOAD_LDS16(kg, (bf16_t*)Klds[0] + tid * 8);
  GLOAD_LDS16(vg, (bf16_t*)Vlds[0] + tid * 8);

  for (int step = 0; step < 16; ++step) {
    const int buf = step & 1;
    if (step < 15) {
      GLOAD_LDS16(kg + (step + 1) * 4096, (bf16_t*)Klds[buf ^ 1] + tid * 8);
      GLOAD_LDS16(vg + (step + 1) * 64, (bf16_t*)Vlds[buf ^ 1] + tid * 8);
      asm volatile("s_waitcnt vmcnt(2)" ::: "memory");
    } else {
      asm volatile("s_waitcnt vmcnt(0)" ::: "memory");
    }
    __builtin_amdgcn_s_barrier();

    const char* Kl = (const char*)Klds[buf];
    const char* Vl = (const char*)Vlds[buf];

    f32x16 S0 = {}, S1 = {};
#pragma unroll
    for (int kc = 0; kc < 4; ++kc) {
      const int off = (rbase + kc * 32) ^ rswz;
      bf16x8 kf0 = *(const bf16x8*)(Kl + off);
      bf16x8 kf1 = *(const bf16x8*)(Kl + off + 4096);
      S0 = MFMA32(kf0, qf[kc], S0);
      S1 = MFMA32(kf1, qf[kc], S1);
    }

    float pm = fmaxf(S0[0], S1[0]);
#pragma unroll
    for (int r = 1; r < 16; ++r) pm = fmaxf(pm, fmaxf(S0[r], S1[r]));
    pm = fmaxf(pm, __shfl_xor(pm, 32));
    if (__any(pm > m + 8.f)) {           // defer-max, THR=8 (log2 domain)
      const float mnew = fmaxf(m, pm);
      const float corr = __builtin_amdgcn_exp2f(m - mnew);
      m = mnew;
      lsum *= corr;
      const int ci = __builtin_bit_cast(int, corr);
#pragma unroll
      for (int r = 0; r < 16; ++r) {
        const int qsel = (r & 3) + 8 * (r >> 2) + 4 * q5;
        const float cr = __builtin_bit_cast(
            float, __builtin_amdgcn_ds_bpermute(qsel << 2, ci));
        O0[r] *= cr;
        O1[r] *= cr;
      }
    }
    float ps = 0.f;
#pragma unroll
    for (int r = 0; r < 16; ++r) {
      float p = __builtin_amdgcn_exp2f(S0[r] - m);
      ps += p; S0[r] = p;
      p = __builtin_amdgcn_exp2f(S1[r] - m);
      ps += p; S1[r] = p;
    }
    lsum += ps;

#define MAKE_PA(PV, B0, PA)                            \
  {                                                    \
    unsigned a_ = cvtpk(PV[B0 + 0], PV[B0 + 1]);       \
    unsigned b_ = cvtpk(PV[B0 + 2], PV[B0 + 3]);       \
    unsigned c_ = cvtpk(PV[B0 + 4], PV[B0 + 5]);       \
    unsigned d_ = cvtpk(PV[B0 + 6], PV[B0 + 7]);       \
    pl32swap(a_, c_);                                  \
    pl32swap(b_, d_);                                  \
    i32x4 wv_;                                         \
    wv_[0] = a_; wv_[1] = b_; wv_[2] = c_; wv_[3] = d_; \
    PA = __builtin_bit_cast(bf16x8, wv_);              \
  }
#define PV_STEP(PV, B0, KS)                                       \
  {                                                               \
    bf16x8 pa;                                                    \
    MAKE_PA(PV, B0, pa);                                          \
    const int voff = (rbase + (KS) * 32) ^ rswz;                  \
    bf16x8 vf0 = *(const bf16x8*)(Vl + voff);                     \
    bf16x8 vf1 = *(const bf16x8*)(Vl + voff + 4096);              \
    O0 = MFMA32(pa, vf0, O0);                                     \
    O1 = MFMA32(pa, vf1, O1);                                     \
  }
    PV_STEP(S0, 0, 0)
    PV_STEP(S0, 8, 1)
    PV_STEP(S1, 0, 2)
    PV_STEP(S1, 8, 3)

    __builtin_amdgcn_s_barrier();
  }

  lsum += __shfl_xor(lsum, 32);
  const float rinv = 1.f / lsum;
  const int ri = __builtin_bit_cast(int, rinv);
  const int bb = bh >> 4, h = bh & 15;
  bf16_t* Xb = X + (size_t)bb * 1024 * 1024 + h * 64;
#pragma unroll
  for (int r = 0; r < 16; ++r) {
    const int qsel = (r & 3) + 8 * (r >> 2) + 4 * q5;
    const float rv = __builtin_bit_cast(
        float, __builtin_amdgcn_ds_bpermute(qsel << 2, ri));
    const size_t rowoff = (size_t)(qbase + qsel) * 1024;
    Xb[rowoff + k32] = (bf16_t)(O0[r] * rv);
    Xb[rowoff + 32 + k32] = (bf16_t)(O1[r] * rv);
  }
}

// --------------------------------------------------------------- launch ----
extern "C" void kernel_launch(void* const* d_in, const int* in_sizes, int n_in,
                              void* d_out, int out_size, void* d_ws,
                              size_t ws_size, hipStream_t stream) {
  const float* x = (const float*)d_in[0];
  const int* em = (const int*)d_in[1];
  const float* qkvw = (const float*)d_in[2];
  const float* projw = (const float*)d_in[3];
  const float* projb = (const float*)d_in[4];
  float* out = (float*)d_out;

  char* ws = (char*)d_ws;
  size_t off = 0;
  bf16_t* xin = (bf16_t*)(ws + off); off += (size_t)16384 * 1024 * 2;  // reused as Xattn
  bf16_t* wq  = (bf16_t*)(ws + off); off += (size_t)3072 * 1024 * 2;
  bf16_t* wp  = (bf16_t*)(ws + off); off += (size_t)1024 * 1024 * 2;
  bf16_t* Qb  = (bf16_t*)(ws + off); off += (size_t)256 * 1024 * 64 * 2;
  bf16_t* Kb  = (bf16_t*)(ws + off); off += (size_t)256 * 1024 * 64 * 2;
  bf16_t* VTb = (bf16_t*)(ws + off); off += (size_t)256 * 64 * 1024 * 2;
  int* perm   = (int*)(ws + off); off += 16384 * 4;   // perm[b*1024+np] = n
  int* ems    = (int*)(ws + off); off += 16384 * 4;   // expert of sorted slot

  // per-batch counting sort (deterministic bucket structure)
  sort_batch<<<16, 256, 0, stream>>>(em, perm, ems);

  // gather tokens into permuted order + mask + bf16
  prep_tokens<<<16384, 256, 0, stream>>>(x, perm, ems, xin);
  conv_w<<<3072, 256, 0, stream>>>(qkvw, wq);
  conv_w<<<1024, 256, 0, stream>>>(projw, wp);

  // QKV: M=16384 (permuted space, nested-K), N=3072 -> 64x12 blocks
  gemm256<0><<<768, 512, 0, stream>>>(
      xin, wq, 1024, perm, ems, Qb, Kb, VTb, nullptr, nullptr);

  // attention in permuted space: 4 q-tiles x 256 (b,h); X -> xin region
  attn256<<<dim3(4, 256), 512, 0, stream>>>(Qb, Kb, VTb, xin);

  // proj: M=16384 (permuted), N=1024, masked-block skip, scatter epilogue
  gemm256<1><<<256, 512, 0, stream>>>(
      xin, wp, 1024, perm, ems, nullptr, nullptr, nullptr, out, projb);
}

// Round 10
// 302.988 us; speedup vs baseline: 3.9755x; 3.9755x over previous
//
#include <hip/hip_runtime.h>
#include <hip/hip_bf16.h>

// NestedAttention: B=16,N=1024,D=1024,E=4,H=16,hd=64
// bf16 MFMA pipeline with fp32 accumulate.
// R10: m201 8-phase GEMM schedule (counted vmcnt(4), never drained in-loop;
// 2 K-tiles per iteration, half-tile staging with liveness-ledger ordering).
// Per-batch expert sort; pipeline in permuted token space; nested-K QKV;
// masked-block-skip proj; T2 chunk-swizzle; T5 setprio around MFMA clusters.

typedef __bf16 bf16_t;
typedef __bf16 bf16x8 __attribute__((ext_vector_type(8)));
typedef __bf16 bf16x4 __attribute__((ext_vector_type(4)));
typedef float f32x4 __attribute__((ext_vector_type(4)));
typedef float f32x16 __attribute__((ext_vector_type(16)));
typedef int i32x4 __attribute__((ext_vector_type(4)));

typedef __attribute__((address_space(1))) void gvoid;
typedef __attribute__((address_space(3))) void lvoid;

#define MFMA16(a, b, c) __builtin_amdgcn_mfma_f32_16x16x32_bf16((a), (b), (c), 0, 0, 0)
#define MFMA32(a, b, c) __builtin_amdgcn_mfma_f32_32x32x16_bf16((a), (b), (c), 0, 0, 0)
#define GLOAD_LDS16(gsrc, ldst) \
  __builtin_amdgcn_global_load_lds((gvoid*)(gsrc), (lvoid*)(ldst), 16, 0, 0)

// softmax scale 1/sqrt(64) folded with log2(e) into Q at QKV epilogue
#define QSCALE 0.18033688f

__device__ __forceinline__ unsigned cvtpk(float lo, float hi) {
  unsigned r;
  asm("v_cvt_pk_bf16_f32 %0, %1, %2" : "=v"(r) : "v"(lo), "v"(hi));
  return r;
}
__device__ __forceinline__ void pl32swap(unsigned& x, unsigned& y) {
  asm("v_permlane32_swap_b32 %0, %1" : "+v"(x), "+v"(y));
}

// ------------------------------------------------------------- sorting ----
// Per-batch counting sort (16 batches x 1024 tokens) into ascending-expert
// order. perm[b*1024+np] = original n; ems[b*1024+np] = expert. Bucket
// boundaries deterministic; within-bucket order race-dependent but every
// output row depends only on its own token -> bit-identical outputs.
__global__ __launch_bounds__(256) void sort_batch(
    const int* __restrict__ em, int* __restrict__ perm, int* __restrict__ ems) {
  __shared__ int cnt[4], base[4], cur[4];
  const int b = blockIdx.x, t = threadIdx.x;
  if (t < 4) cnt[t] = 0;
  __syncthreads();
  int e[4];
#pragma unroll
  for (int i = 0; i < 4; ++i) {
    e[i] = em[b * 1024 + t * 4 + i];
    atomicAdd(&cnt[e[i]], 1);
  }
  __syncthreads();
  if (t == 0) {
    base[0] = 0; base[1] = cnt[0];
    base[2] = cnt[0] + cnt[1]; base[3] = cnt[0] + cnt[1] + cnt[2];
    cur[0] = cur[1] = cur[2] = cur[3] = 0;
  }
  __syncthreads();
#pragma unroll
  for (int i = 0; i < 4; ++i) {
    const int pos = base[e[i]] + atomicAdd(&cur[e[i]], 1);
    perm[b * 1024 + pos] = t * 4 + i;
    ems[b * 1024 + pos] = e[i];
  }
}

// ---------------------------------------------------------------- prep ----
__global__ __launch_bounds__(256) void prep_tokens(
    const float* __restrict__ x, const int* __restrict__ perm,
    const int* __restrict__ ems, bf16_t* __restrict__ xq) {
  const int prow = blockIdx.x;                // permuted row 0..16383
  const int orig = (prow & ~1023) + perm[prow];
  const int dt = 128 << ems[prow];            // token's nested dim
  const int d = threadIdx.x * 4;
  float4 v = ((const float4*)(x + (size_t)orig * 1024))[threadIdx.x];
  const bool keep = d < dt;                   // dt multiple of 128 -> uniform per 4
  bf16x4 o;
  o[0] = (bf16_t)(keep ? v.x : 0.f);
  o[1] = (bf16_t)(keep ? v.y : 0.f);
  o[2] = (bf16_t)(keep ? v.z : 0.f);
  o[3] = (bf16_t)(keep ? v.w : 0.f);
  *((bf16x4*)(xq + (size_t)prow * 1024 + d)) = o;
}

__global__ __launch_bounds__(256) void conv_w(
    const float* __restrict__ s, bf16_t* __restrict__ dvec) {
  const int i = blockIdx.x * 256 + threadIdx.x;  // grid sized exactly, no guard
  float4 v = ((const float4*)s)[i];
  bf16x4 o;
  o[0] = (bf16_t)v.x; o[1] = (bf16_t)v.y; o[2] = (bf16_t)v.z; o[3] = (bf16_t)v.w;
  ((bf16x4*)dvec)[i] = o;
}

// ---------------------------------------------------------------- GEMM ----
// C[m,f] = sum_k A[m,k] * Bw[f,k]  ("B^T" GEMM), permuted-space rows.
// 256x256 tile, BK=64, 8 waves (2Mx4N). m201 8-phase schedule:
//   iter = 2 K-tiles (t->buf0, t+1->buf1); phase = {ds_read quadrant frags;
//   stage 1 half-tile (2 gloads); s_barrier; setprio(1); 16 MFMA;
//   setprio(0); [vmcnt(4) at ph4/ph8 only]; s_barrier}.
// Liveness ledger (stage half H only after its last reader phase):
//   A(buf0) read ph1,ph3 -> Al/Ah(t+2) staged ph4/ph5. B(buf0) read ph1,ph2
//   -> Bl/Bh(t+2) staged ph3/ph6. A(buf1) read ph5,ph7 -> Al(t+3) ph8.
//   B(buf1) read ph5,ph6 -> Bl(t+3) ph7. Ah/Bh(t+1) staged ph1/ph2.
// Steady state: 4 loads (2 half-tiles) always in flight; vmcnt(4) retires
// exactly what the next phases need. NT is always even (2*2^e).
// EPI 0 (QKV): K-loop to block's dtmax; scatter q(scaled)/k/vT (permuted).
// EPI 1 (proj): full K; colbase >= dtmax -> zero-store fast path.
template <int EPI>
__global__ __launch_bounds__(512, 2) void gemm256(
    const bf16_t* __restrict__ A, const bf16_t* __restrict__ Bw, int K,
    const int* __restrict__ perm, const int* __restrict__ ems,
    bf16_t* __restrict__ qo, bf16_t* __restrict__ ko, bf16_t* __restrict__ vto,
    float* __restrict__ yout, const float* __restrict__ bias) {
  __shared__ bf16_t lds[2][32768];  // per buf: A 32KB + B 32KB (chunk-swizzled)
  const int tid = threadIdx.x;
  const int lane = tid & 63, w = tid >> 6;
  const int wm = w >> 2, wn = w & 3;
  const int g = lane >> 4, c16 = lane & 15;

  const int bid = blockIdx.x;
  const int rowbase = (bid & 63) * 256;   // row-blocks cycle fastest (balance)
  const int colbase = (bid >> 6) * 256;

  const int dtmax = 128 << ems[rowbase + 255];

  if constexpr (EPI == 1) {
    if (colbase >= dtmax) {  // whole block masked -> write zero rows, done
      const float4 z = make_float4(0.f, 0.f, 0.f, 0.f);
#pragma unroll
      for (int i = 0; i < 32; ++i) {
        const int idx = i * 512 + tid;
        const int r = idx >> 6, c4 = idx & 63;
        const int orow = ((rowbase + r) & ~1023) + perm[rowbase + r];
        ((float4*)(yout + (size_t)orow * 1024 + colbase))[c4] = z;
      }
      return;
    }
  }

  const int NT = (EPI == 0) ? (dtmax >> 6) : (K >> 6);  // even: 2,4,8,16

  // staging: linear LDS dest, inverse-swizzled global source (rule #21).
  // STAGE(j): j=0,1 -> A-low half; 2,3 -> A-high; 4,5 -> B-low; 6,7 -> B-high
  const int trow = tid >> 3;
  const int scol = (((tid & 7) ^ (trow & 7)) << 3);
  const bf16_t* pa = A + (size_t)(rowbase + trow) * K + scol;
  const bf16_t* pb = Bw + (size_t)(colbase + trow) * K + scol;

#define STAGE(j, koff, dst)                                       \
  GLOAD_LDS16(((j) < 4 ? pa + (size_t)((j) * 64) * K              \
                       : pb + (size_t)(((j) - 4) * 64) * K) +     \
                  (koff),                                         \
              (dst) + ((j) * 512 + tid) * 8)

#define LDFRAG(base, R, kk)            \
  (*(const bf16x8*)((base) + (size_t)(R) * 64 + \
                    (((((kk) << 2) + g) ^ (c16 & 7)) << 3)))

#define LD_A4(F, BASE, ROFF)                                         \
  _Pragma("unroll") for (int mi = 0; mi < 4; ++mi)                   \
  _Pragma("unroll") for (int kk = 0; kk < 2; ++kk)                   \
      F[mi][kk] = LDFRAG((BASE), wm * 128 + ((ROFF) + mi) * 16 + c16, kk);
#define LD_B2(F, BASE, NOFF)                                         \
  _Pragma("unroll") for (int ni = 0; ni < 2; ++ni)                   \
  _Pragma("unroll") for (int kk = 0; kk < 2; ++kk)                   \
      F[ni][kk] = LDFRAG((BASE), wn * 64 + ((NOFF) + ni) * 16 + c16, kk);
#define QUAD(MOFF, NOFF, AF, BF)                                     \
  _Pragma("unroll") for (int mi = 0; mi < 4; ++mi)                   \
  _Pragma("unroll") for (int ni = 0; ni < 2; ++ni)                   \
  _Pragma("unroll") for (int kk = 0; kk < 2; ++kk)                   \
      acc[(MOFF) + mi][(NOFF) + ni] =                                \
          MFMA16(AF[mi][kk], BF[ni][kk], acc[(MOFF) + mi][(NOFF) + ni]);

#define SB __builtin_amdgcn_sched_barrier(0)
#define BAR __builtin_amdgcn_s_barrier()
#define PRIO(x) __builtin_amdgcn_s_setprio(x)
#define VM4 asm volatile("s_waitcnt vmcnt(4)" ::: "memory")
#define VM0 asm volatile("s_waitcnt vmcnt(0)" ::: "memory")

  f32x4 acc[8][4] = {};
  bf16_t* const L0 = (bf16_t*)lds[0];
  bf16_t* const L1 = (bf16_t*)lds[1];
  const bf16_t* const L0B = L0 + 16384;
  const bf16_t* const L1B = L1 + 16384;

  // prologue: tile0 fully -> buf0; tile1 A-low + B-low -> buf1.
#pragma unroll
  for (int j = 0; j < 8; ++j) STAGE(j, 0, L0);
  STAGE(0, 64, L1); STAGE(1, 64, L1);
  STAGE(4, 64, L1); STAGE(5, 64, L1);
  VM4;  // tile0 landed; tile1's 4 loads stay in flight
  BAR; SB;

  for (int t = 0; t < NT; t += 2) {
    const int k1 = (t + 1) << 6, k2 = (t + 2) << 6, k3 = (t + 3) << 6;
    const bool pf = (t + 2) < NT;
    bf16x8 af[4][2], b0[2][2], b1[2][2];

    // ---- ph1: Q0(t)  [reads A-low/high(buf0) af, B-low/high(buf0) b0]
    LD_A4(af, L0, 0);
    LD_B2(b0, L0B, 0);
    SB;
    STAGE(2, k1, L1); STAGE(3, k1, L1);   // A-high(t+1)
    BAR; PRIO(1);
    QUAD(0, 0, af, b0);
    PRIO(0); BAR; SB;

    // ---- ph2: Q1(t)  [reads b1(buf0); last B(buf0) reads]
    LD_B2(b1, L0B, 2);
    SB;
    STAGE(6, k1, L1); STAGE(7, k1, L1);   // B-high(t+1)
    BAR; PRIO(1);
    QUAD(0, 2, af, b1);
    PRIO(0); BAR; SB;

    // ---- ph3: Q2(t)  [reads af2->af (buf0 A); last A(buf0) reads]
    LD_A4(af, L0, 4);
    SB;
    if (pf) { STAGE(4, k2, L0); STAGE(5, k2, L0); }  // B-low(t+2): B(buf0) dead
    BAR; PRIO(1);
    QUAD(4, 0, af, b0);
    PRIO(0); BAR; SB;

    // ---- ph4: Q3(t) from held regs; stage A-low(t+2); counted wait
    if (pf) { STAGE(0, k2, L0); STAGE(1, k2, L0); }  // A(buf0) dead after ph3
    PRIO(1);
    QUAD(4, 2, af, b1);
    PRIO(0);
    if (pf) { VM4; } else { VM0; }  // tile t+1 halves landed
    BAR; SB;

    // ---- ph5: Q0(t+1)
    LD_A4(af, L1, 0);
    LD_B2(b0, L1B, 0);
    SB;
    if (pf) { STAGE(2, k2, L0); STAGE(3, k2, L0); }  // A-high(t+2)
    BAR; PRIO(1);
    QUAD(0, 0, af, b0);
    PRIO(0); BAR; SB;

    // ---- ph6: Q1(t+1)  [last B(buf1) reads]
    LD_B2(b1, L1B, 2);
    SB;
    if (pf) { STAGE(6, k2, L0); STAGE(7, k2, L0); }  // B-high(t+2)
    BAR; PRIO(1);
    QUAD(0, 2, af, b1);
    PRIO(0); BAR; SB;

    // ---- ph7: Q2(t+1)  [last A(buf1) reads]
    LD_A4(af, L1, 4);
    SB;
    if (pf) { STAGE(4, k3, L1); STAGE(5, k3, L1); }  // B-low(t+3): B(buf1) dead
    BAR; PRIO(1);
    QUAD(4, 0, af, b0);
    PRIO(0); BAR; SB;

    // ---- ph8: Q3(t+1); stage A-low(t+3); counted wait
    if (pf) { STAGE(0, k3, L1); STAGE(1, k3, L1); }  // A(buf1) dead after ph7
    PRIO(1);
    QUAD(4, 2, af, b1);
    PRIO(0);
    if (pf) { VM4; } else { VM0; }  // tile t+2 fully landed
    BAR; SB;
  }

  // C/D layout: col = lane&15, row = (lane>>4)*4 + reg  [m89/m91 verified]
  if constexpr (EPI == 0) {
    const int s = colbase >> 10;  // 0=q,1=k,2=v (uniform per block: 256|1024)
#pragma unroll
    for (int mi = 0; mi < 8; ++mi)
#pragma unroll
      for (int j = 0; j < 4; ++j) {
        const int row = rowbase + wm * 128 + mi * 16 + g * 4 + j;  // permuted
        const int bb = row >> 10, n = row & 1023;  // n = permuted position
#pragma unroll
        for (int ni = 0; ni < 4; ++ni) {
          const int col = colbase + wn * 64 + ni * 16 + c16;  // f
          const float v = acc[mi][ni][j];
          const int h = (col >> 6) & 15, e = col & 63;
          const size_t bh = (size_t)(bb * 16 + h);
          if (s == 0)
            qo[(bh * 1024 + n) * 64 + e] = (bf16_t)(v * QSCALE);
          else if (s == 1)
            ko[(bh * 1024 + n) * 64 + e] = (bf16_t)v;
          else
            vto[(bh * 64 + e) * 1024 + n] = (bf16_t)v;  // V transposed
        }
      }
  } else {
#pragma unroll
    for (int mi = 0; mi < 8; ++mi)
#pragma unroll
      for (int j = 0; j < 4; ++j) {
        const int row = rowbase + wm * 128 + mi * 16 + g * 4 + j;  // permuted
        const int dt = 128 << ems[row];
        const int orow = (row & ~1023) + perm[row];  // original token row
#pragma unroll
        for (int ni = 0; ni < 4; ++ni) {
          const int col = colbase + wn * 64 + ni * 16 + c16;
          const float v = acc[mi][ni][j] + bias[col];
          yout[(size_t)orow * 1024 + col] = (col < dt) ? v : 0.f;
        }
      }
  }
#undef STAGE
#undef LDFRAG
#undef LD_A4
#undef LD_B2
#undef QUAD
#undef SB
#undef BAR
#undef PRIO
#undef VM4
#undef VM0
}

// ----------------------------------------------------------- attention ----
// Runs entirely in permuted token space (softmax over a batch's keys is
// permutation-invariant; each output row is its own query's result).
// 8 waves x 32 q-rows = 256 q rows / block. KVBLK=64 double-buffered in LDS
// (K row-major [64key][64d], V^T [64d][64key], both XOR-swizzled).
// Swapped QK^T: S = mfma32(Kfrag, Qfrag) -> lane holds P-row slice for
// q = lane&31 in registers; softmax fully in-register; P->bf16 via
// cvt_pk + permlane32_swap feeds PV's A operand directly.
__global__ __launch_bounds__(512, 2) void attn256(
    const bf16_t* __restrict__ Q, const bf16_t* __restrict__ Kb,
    const bf16_t* __restrict__ VT, bf16_t* __restrict__ X) {
  __shared__ bf16_t Klds[2][4096];
  __shared__ bf16_t Vlds[2][4096];
  const int tid = threadIdx.x;
  const int w = tid >> 6, lane = tid & 63;
  const int k32 = lane & 31, q5 = lane >> 5;
  const int bh = blockIdx.y;
  const int qbase = blockIdx.x * 256 + w * 32;

  const bf16_t* Qbh = Q + (size_t)bh * 65536;
  const bf16_t* Kbh = Kb + (size_t)bh * 65536;
  const bf16_t* Vbh = VT + (size_t)bh * 65536;

  const int trow = tid >> 3;
  const int tslot = (tid & 7) ^ (trow & 7);
  const bf16_t* kg = Kbh + (size_t)trow * 64 + tslot * 8;
  const bf16_t* vg = Vbh + (size_t)trow * 1024 + tslot * 8;

  bf16x8 qf[4];
#pragma unroll
  for (int kc = 0; kc < 4; ++kc)
    qf[kc] = *(const bf16x8*)(Qbh + (size_t)(qbase + k32) * 64 + kc * 16 + q5 * 8);
  asm volatile("" ::"v"(qf[0]), "v"(qf[1]), "v"(qf[2]), "v"(qf[3]));

  const int rbase = k32 * 128 + q5 * 16;
  const int rswz = (k32 & 7) << 4;

  f32x16 O0 = {}, O1 = {};
  float m = -3.0e38f, lsum = 0.f;

  GLOAD_LDS16(kg, (bf16_t*)Klds[0] + tid * 8);
  GLOAD_LDS16(vg, (bf16_t*)Vlds[0] + tid * 8);

  for (int step = 0; step < 16; ++step) {
    const int buf = step & 1;
    if (step < 15) {
      GLOAD_LDS16(kg + (step + 1) * 4096, (bf16_t*)Klds[buf ^ 1] + tid * 8);
      GLOAD_LDS16(vg + (step + 1) * 64, (bf16_t*)Vlds[buf ^ 1] + tid * 8);
      asm volatile("s_waitcnt vmcnt(2)" ::: "memory");
    } else {
      asm volatile("s_waitcnt vmcnt(0)" ::: "memory");
    }
    __builtin_amdgcn_s_barrier();

    const char* Kl = (const char*)Klds[buf];
    const char* Vl = (const char*)Vlds[buf];

    f32x16 S0 = {}, S1 = {};
#pragma unroll
    for (int kc = 0; kc < 4; ++kc) {
      const int off = (rbase + kc * 32) ^ rswz;
      bf16x8 kf0 = *(const bf16x8*)(Kl + off);
      bf16x8 kf1 = *(const bf16x8*)(Kl + off + 4096);
      S0 = MFMA32(kf0, qf[kc], S0);
      S1 = MFMA32(kf1, qf[kc], S1);
    }

    float pm = fmaxf(S0[0], S1[0]);
#pragma unroll
    for (int r = 1; r < 16; ++r) pm = fmaxf(pm, fmaxf(S0[r], S1[r]));
    pm = fmaxf(pm, __shfl_xor(pm, 32));
    if (__any(pm > m + 8.f)) {           // defer-max, THR=8 (log2 domain)
      const float mnew = fmaxf(m, pm);
      const float corr = __builtin_amdgcn_exp2f(m - mnew);
      m = mnew;
      lsum *= corr;
      const int ci = __builtin_bit_cast(int, corr);
#pragma unroll
      for (int r = 0; r < 16; ++r) {
        const int qsel = (r & 3) + 8 * (r >> 2) + 4 * q5;
        const float cr = __builtin_bit_cast(
            float, __builtin_amdgcn_ds_bpermute(qsel << 2, ci));
        O0[r] *= cr;
        O1[r] *= cr;
      }
    }
    float ps = 0.f;
#pragma unroll
    for (int r = 0; r < 16; ++r) {
      float p = __builtin_amdgcn_exp2f(S0[r] - m);
      ps += p; S0[r] = p;
      p = __builtin_amdgcn_exp2f(S1[r] - m);
      ps += p; S1[r] = p;
    }
    lsum += ps;

#define MAKE_PA(PV, B0, PA)                            \
  {                                                    \
    unsigned a_ = cvtpk(PV[B0 + 0], PV[B0 + 1]);       \
    unsigned b_ = cvtpk(PV[B0 + 2], PV[B0 + 3]);       \
    unsigned c_ = cvtpk(PV[B0 + 4], PV[B0 + 5]);       \
    unsigned d_ = cvtpk(PV[B0 + 6], PV[B0 + 7]);       \
    pl32swap(a_, c_);                                  \
    pl32swap(b_, d_);                                  \
    i32x4 wv_;                                         \
    wv_[0] = a_; wv_[1] = b_; wv_[2] = c_; wv_[3] = d_; \
    PA = __builtin_bit_cast(bf16x8, wv_);              \
  }
#define PV_STEP(PV, B0, KS)                                       \
  {                                                               \
    bf16x8 pa;                                                    \
    MAKE_PA(PV, B0, pa);                                          \
    const int voff = (rbase + (KS) * 32) ^ rswz;                  \
    bf16x8 vf0 = *(const bf16x8*)(Vl + voff);                     \
    bf16x8 vf1 = *(const bf16x8*)(Vl + voff + 4096);              \
    O0 = MFMA32(pa, vf0, O0);                                     \
    O1 = MFMA32(pa, vf1, O1);                                     \
  }
    PV_STEP(S0, 0, 0)
    PV_STEP(S0, 8, 1)
    PV_STEP(S1, 0, 2)
    PV_STEP(S1, 8, 3)

    __builtin_amdgcn_s_barrier();
  }

  lsum += __shfl_xor(lsum, 32);
  const float rinv = 1.f / lsum;
  const int ri = __builtin_bit_cast(int, rinv);
  const int bb = bh >> 4, h = bh & 15;
  bf16_t* Xb = X + (size_t)bb * 1024 * 1024 + h * 64;
#pragma unroll
  for (int r = 0; r < 16; ++r) {
    const int qsel = (r & 3) + 8 * (r >> 2) + 4 * q5;
    const float rv = __builtin_bit_cast(
        float, __builtin_amdgcn_ds_bpermute(qsel << 2, ri));
    const size_t rowoff = (size_t)(qbase + qsel) * 1024;
    Xb[rowoff + k32] = (bf16_t)(O0[r] * rv);
    Xb[rowoff + 32 + k32] = (bf16_t)(O1[r] * rv);
  }
}

// --------------------------------------------------------------- launch ----
extern "C" void kernel_launch(void* const* d_in, const int* in_sizes, int n_in,
                              void* d_out, int out_size, void* d_ws,
                              size_t ws_size, hipStream_t stream) {
  const float* x = (const float*)d_in[0];
  const int* em = (const int*)d_in[1];
  const float* qkvw = (const float*)d_in[2];
  const float* projw = (const float*)d_in[3];
  const float* projb = (const float*)d_in[4];
  float* out = (float*)d_out;

  char* ws = (char*)d_ws;
  size_t off = 0;
  bf16_t* xin = (bf16_t*)(ws + off); off += (size_t)16384 * 1024 * 2;  // reused as Xattn
  bf16_t* wq  = (bf16_t*)(ws + off); off += (size_t)3072 * 1024 * 2;
  bf16_t* wp  = (bf16_t*)(ws + off); off += (size_t)1024 * 1024 * 2;
  bf16_t* Qb  = (bf16_t*)(ws + off); off += (size_t)256 * 1024 * 64 * 2;
  bf16_t* Kb  = (bf16_t*)(ws + off); off += (size_t)256 * 1024 * 64 * 2;
  bf16_t* VTb = (bf16_t*)(ws + off); off += (size_t)256 * 64 * 1024 * 2;
  int* perm   = (int*)(ws + off); off += 16384 * 4;   // perm[b*1024+np] = n
  int* ems    = (int*)(ws + off); off += 16384 * 4;   // expert of sorted slot

  // per-batch counting sort (deterministic bucket structure)
  sort_batch<<<16, 256, 0, stream>>>(em, perm, ems);

  // gather tokens into permuted order + mask + bf16
  prep_tokens<<<16384, 256, 0, stream>>>(x, perm, ems, xin);
  conv_w<<<3072, 256, 0, stream>>>(qkvw, wq);
  conv_w<<<1024, 256, 0, stream>>>(projw, wp);

  // QKV: M=16384 (permuted space, nested-K), N=3072 -> 64x12 blocks
  gemm256<0><<<768, 512, 0, stream>>>(
      xin, wq, 1024, perm, ems, Qb, Kb, VTb, nullptr, nullptr);

  // attention in permuted space: 4 q-tiles x 256 (b,h); X -> xin region
  attn256<<<dim3(4, 256), 512, 0, stream>>>(Qb, Kb, VTb, xin);

  // proj: M=16384 (permuted), N=1024, masked-block skip, scatter epilogue
  gemm256<1><<<256, 512, 0, stream>>>(
      xin, wp, 1024, perm, ems, nullptr, nullptr, nullptr, out, projb);
}

// Round 11
// 271.944 us; speedup vs baseline: 4.4293x; 1.1142x over previous
//
#include <hip/hip_runtime.h>
#include <hip/hip_bf16.h>

// NestedAttention: B=16,N=1024,D=1024,E=4,H=16,hd=64
// bf16 MFMA pipeline with fp32 accumulate.
// R11: R7's 2-phase 256^2 GEMM (best measured) + LDS-staged COALESCED
// epilogues: C-tile staged into the (dead) 128KB LDS with XOR swizzle, read
// back b128, stored as dwordx4 (was 128 scalar 2B/4B stores per thread with
// 1.5x partial-line write amp). Per-batch expert sort; permuted-space
// pipeline; nested-K QKV; masked-block-skip proj.

typedef __bf16 bf16_t;
typedef __bf16 bf16x8 __attribute__((ext_vector_type(8)));
typedef __bf16 bf16x4 __attribute__((ext_vector_type(4)));
typedef float f32x4 __attribute__((ext_vector_type(4)));
typedef float f32x16 __attribute__((ext_vector_type(16)));
typedef int i32x4 __attribute__((ext_vector_type(4)));

typedef __attribute__((address_space(1))) void gvoid;
typedef __attribute__((address_space(3))) void lvoid;

#define MFMA16(a, b, c) __builtin_amdgcn_mfma_f32_16x16x32_bf16((a), (b), (c), 0, 0, 0)
#define MFMA32(a, b, c) __builtin_amdgcn_mfma_f32_32x32x16_bf16((a), (b), (c), 0, 0, 0)
#define GLOAD_LDS16(gsrc, ldst) \
  __builtin_amdgcn_global_load_lds((gvoid*)(gsrc), (lvoid*)(ldst), 16, 0, 0)

// softmax scale 1/sqrt(64) folded with log2(e) into Q at QKV epilogue
#define QSCALE 0.18033688f

__device__ __forceinline__ unsigned cvtpk(float lo, float hi) {
  unsigned r;
  asm("v_cvt_pk_bf16_f32 %0, %1, %2" : "=v"(r) : "v"(lo), "v"(hi));
  return r;
}
__device__ __forceinline__ void pl32swap(unsigned& x, unsigned& y) {
  asm("v_permlane32_swap_b32 %0, %1" : "+v"(x), "+v"(y));
}

// ------------------------------------------------------------- sorting ----
// Per-batch counting sort (16 batches x 1024 tokens) into ascending-expert
// order. perm[b*1024+np] = original n; ems[b*1024+np] = expert. Bucket
// boundaries deterministic; within-bucket order race-dependent but every
// output row depends only on its own token -> bit-identical outputs.
__global__ __launch_bounds__(256) void sort_batch(
    const int* __restrict__ em, int* __restrict__ perm, int* __restrict__ ems) {
  __shared__ int cnt[4], base[4], cur[4];
  const int b = blockIdx.x, t = threadIdx.x;
  if (t < 4) cnt[t] = 0;
  __syncthreads();
  int e[4];
#pragma unroll
  for (int i = 0; i < 4; ++i) {
    e[i] = em[b * 1024 + t * 4 + i];
    atomicAdd(&cnt[e[i]], 1);
  }
  __syncthreads();
  if (t == 0) {
    base[0] = 0; base[1] = cnt[0];
    base[2] = cnt[0] + cnt[1]; base[3] = cnt[0] + cnt[1] + cnt[2];
    cur[0] = cur[1] = cur[2] = cur[3] = 0;
  }
  __syncthreads();
#pragma unroll
  for (int i = 0; i < 4; ++i) {
    const int pos = base[e[i]] + atomicAdd(&cur[e[i]], 1);
    perm[b * 1024 + pos] = t * 4 + i;
    ems[b * 1024 + pos] = e[i];
  }
}

// ---------------------------------------------------------------- prep ----
__global__ __launch_bounds__(256) void prep_tokens(
    const float* __restrict__ x, const int* __restrict__ perm,
    const int* __restrict__ ems, bf16_t* __restrict__ xq) {
  const int prow = blockIdx.x;                // permuted row 0..16383
  const int orig = (prow & ~1023) + perm[prow];
  const int dt = 128 << ems[prow];            // token's nested dim
  const int d = threadIdx.x * 4;
  float4 v = ((const float4*)(x + (size_t)orig * 1024))[threadIdx.x];
  const bool keep = d < dt;                   // dt multiple of 128 -> uniform per 4
  bf16x4 o;
  o[0] = (bf16_t)(keep ? v.x : 0.f);
  o[1] = (bf16_t)(keep ? v.y : 0.f);
  o[2] = (bf16_t)(keep ? v.z : 0.f);
  o[3] = (bf16_t)(keep ? v.w : 0.f);
  *((bf16x4*)(xq + (size_t)prow * 1024 + d)) = o;
}

__global__ __launch_bounds__(256) void conv_w(
    const float* __restrict__ s, bf16_t* __restrict__ dvec) {
  const int i = blockIdx.x * 256 + threadIdx.x;  // grid sized exactly, no guard
  float4 v = ((const float4*)s)[i];
  bf16x4 o;
  o[0] = (bf16_t)v.x; o[1] = (bf16_t)v.y; o[2] = (bf16_t)v.z; o[3] = (bf16_t)v.w;
  ((bf16x4*)dvec)[i] = o;
}

// ---------------------------------------------------------------- GEMM ----
// C[m,f] = sum_k A[m,k] * Bw[f,k]  ("B^T" GEMM), permuted-space rows.
// 256x256 tile, BK=64, 8 waves (2Mx4N), R7 2-phase K-loop (stage next tile
// first, compute, single vmcnt(0)+barrier per tile), T2 chunk-swizzle.
// Epilogues stage the C-tile into the now-dead 128KB LDS (XOR-swizzled,
// conflict-checked) and emit only dwordx4 coalesced global stores.
// EPI 0 (QKV): nested K to dtmax; Q/K staged [r][c], V staged transposed
//   [c][r] so V^T writes are contiguous-n 16B runs. QSCALE folded at stage.
// EPI 1 (proj): full K; colbase >= dtmax -> zero-row fast path; else two
//   128-row f32 passes; bias+mask+perm-scatter at readout as float4 rows.
template <int EPI>
__global__ __launch_bounds__(512, 2) void gemm256(
    const bf16_t* __restrict__ A, const bf16_t* __restrict__ Bw, int K,
    const int* __restrict__ perm, const int* __restrict__ ems,
    bf16_t* __restrict__ qo, bf16_t* __restrict__ ko, bf16_t* __restrict__ vto,
    float* __restrict__ yout, const float* __restrict__ bias) {
  __shared__ bf16_t lds[2][32768];  // K-loop dbuf; reused as 128KB epi stage
  const int tid = threadIdx.x;
  const int lane = tid & 63, w = tid >> 6;
  const int wm = w >> 2, wn = w & 3;
  const int g = lane >> 4, c16 = lane & 15;

  const int bid = blockIdx.x;
  const int rowbase = (bid & 63) * 256;   // row-blocks cycle fastest (balance)
  const int colbase = (bid >> 6) * 256;

  const int dtmax = 128 << ems[rowbase + 255];

  if constexpr (EPI == 1) {
    if (colbase >= dtmax) {  // whole block masked -> write zero rows, done
      const float4 z = make_float4(0.f, 0.f, 0.f, 0.f);
#pragma unroll
      for (int i = 0; i < 32; ++i) {
        const int idx = i * 512 + tid;
        const int r = idx >> 6, c4 = idx & 63;
        const int orow = ((rowbase + r) & ~1023) + perm[rowbase + r];
        ((float4*)(yout + (size_t)orow * 1024 + colbase))[c4] = z;
      }
      return;
    }
  }

  const int NT = (EPI == 0) ? (dtmax >> 6) : (K >> 6);

  // staging: thread stages 8x16B chunks/K-tile; linear LDS dest, inverse-
  // swizzled global source (chunk col = (tid&7) ^ (row&7); rule #21).
  const int trow = tid >> 3;
  const int scol = (((tid & 7) ^ (trow & 7)) << 3);
  const bf16_t* pa = A + (size_t)(rowbase + trow) * K + scol;
  const bf16_t* pb = Bw + (size_t)(colbase + trow) * K + scol;

#define STAGE(j, koff, dst)                                       \
  GLOAD_LDS16(((j) < 4 ? pa + (size_t)((j) * 64) * K              \
                       : pb + (size_t)(((j) - 4) * 64) * K) +     \
                  (koff),                                         \
              (dst) + ((j) * 512 + tid) * 8)

#define LDFRAG(base, R, kk)            \
  (*(const bf16x8*)((base) + (size_t)(R) * 64 + \
                    (((((kk) << 2) + g) ^ (c16 & 7)) << 3)))

  f32x4 acc[8][4] = {};

  // prologue: stage K-tile 0, drain, publish
#pragma unroll
  for (int j = 0; j < 8; ++j) STAGE(j, 0, (bf16_t*)lds[0]);
  asm volatile("s_waitcnt vmcnt(0)" ::: "memory");
  __builtin_amdgcn_s_barrier();

  for (int t = 0; t < NT; ++t) {
    const bf16_t* Lb = lds[t & 1];
    const bf16_t* LbB = Lb + 16384;
    const bool pf = (t + 1) < NT;

    if (pf) {  // issue next-tile staging FIRST (lands under this compute)
      bf16_t* Sd = (bf16_t*)lds[(t + 1) & 1];
      const int koff = (t + 1) << 6;
#pragma unroll
      for (int j = 0; j < 8; ++j) STAGE(j, koff, Sd);
    }

    bf16x8 af[4][2], af2[4][2], b0[2][2], b1[2][2];
#pragma unroll
    for (int mi = 0; mi < 4; ++mi)
#pragma unroll
      for (int kk = 0; kk < 2; ++kk)
        af[mi][kk] = LDFRAG(Lb, wm * 128 + mi * 16 + c16, kk);
#pragma unroll
    for (int ni = 0; ni < 2; ++ni)
#pragma unroll
      for (int kk = 0; kk < 2; ++kk)
        b0[ni][kk] = LDFRAG(LbB, wn * 64 + ni * 16 + c16, kk);
#pragma unroll
    for (int mi = 0; mi < 4; ++mi)
#pragma unroll
      for (int ni = 0; ni < 2; ++ni)
#pragma unroll
        for (int kk = 0; kk < 2; ++kk)
          acc[mi][ni] = MFMA16(af[mi][kk], b0[ni][kk], acc[mi][ni]);

#pragma unroll
    for (int ni = 0; ni < 2; ++ni)
#pragma unroll
      for (int kk = 0; kk < 2; ++kk)
        b1[ni][kk] = LDFRAG(LbB, wn * 64 + (ni + 2) * 16 + c16, kk);
#pragma unroll
    for (int mi = 0; mi < 4; ++mi)
#pragma unroll
      for (int ni = 0; ni < 2; ++ni)
#pragma unroll
        for (int kk = 0; kk < 2; ++kk)
          acc[mi][ni + 2] = MFMA16(af[mi][kk], b1[ni][kk], acc[mi][ni + 2]);

#pragma unroll
    for (int mi = 0; mi < 4; ++mi)
#pragma unroll
      for (int kk = 0; kk < 2; ++kk)
        af2[mi][kk] = LDFRAG(Lb, wm * 128 + (mi + 4) * 16 + c16, kk);
#pragma unroll
    for (int mi = 0; mi < 4; ++mi)
#pragma unroll
      for (int ni = 0; ni < 2; ++ni)
#pragma unroll
        for (int kk = 0; kk < 2; ++kk)
          acc[mi + 4][ni] = MFMA16(af2[mi][kk], b0[ni][kk], acc[mi + 4][ni]);

#pragma unroll
    for (int mi = 0; mi < 4; ++mi)
#pragma unroll
      for (int ni = 0; ni < 2; ++ni)
#pragma unroll
        for (int kk = 0; kk < 2; ++kk)
          acc[mi + 4][ni + 2] = MFMA16(af2[mi][kk], b1[ni][kk], acc[mi + 4][ni + 2]);

    if (pf) asm volatile("s_waitcnt vmcnt(0)" ::: "memory");
    __builtin_amdgcn_s_barrier();  // also frees LDS for the epilogue
  }

  // ---- epilogue: LDS-staged, coalesced dwordx4 stores ----
  // C/D frag layout: col = lane&15, row = (lane>>4)*4 + reg [m89/m91].
  char* epi = (char*)lds;  // 131072 B = exactly one 256x256 bf16 tile
  if constexpr (EPI == 0) {
    const int s = colbase >> 10;          // 0=q, 1=k, 2=v (uniform per block)
    const float qs = (s == 0) ? QSCALE : 1.0f;
    if (s < 2) {
      // stage [r][c], col XOR'd by g=(r>>2)&3 (write 2-way = free)
#pragma unroll
      for (int mi = 0; mi < 8; ++mi)
#pragma unroll
        for (int ni = 0; ni < 4; ++ni)
#pragma unroll
          for (int j = 0; j < 4; ++j) {
            const int r = wm * 128 + mi * 16 + g * 4 + j;
            const int c = wn * 64 + ni * 16 + c16;
            *(bf16_t*)(epi + r * 512 + 2 * (c ^ (g << 4))) =
                (bf16_t)(acc[mi][ni][j] * qs);
          }
      __builtin_amdgcn_s_barrier();
      bf16_t* const dstbase = (s == 0) ? qo : ko;
#pragma unroll
      for (int it = 0; it < 16; ++it) {
        const int flat = it * 512 + tid;
        const int r = flat >> 5, c0 = (flat & 31) * 8;
        const int gr = (r >> 2) & 3;
        bf16x8 v = *(const bf16x8*)(epi + r * 512 + 2 * (c0 ^ (gr << 4)));
        const int prow = rowbase + r;
        const int bb = prow >> 10, n = prow & 1023;
        const int f = colbase + c0;
        const int h = (f >> 6) & 15, e = f & 63;
        const size_t bh = (size_t)(bb * 16 + h);
        *(bf16x8*)(dstbase + (bh * 1024 + n) * 64 + e) = v;
      }
    } else {
      // stage transposed [c][r], row XOR'd by (c16>>2)&3 (write 4-way)
#pragma unroll
      for (int mi = 0; mi < 8; ++mi)
#pragma unroll
        for (int ni = 0; ni < 4; ++ni)
#pragma unroll
          for (int j = 0; j < 4; ++j) {
            const int r = wm * 128 + mi * 16 + g * 4 + j;
            const int c = wn * 64 + ni * 16 + c16;
            *(bf16_t*)(epi + c * 512 + 2 * (r ^ ((c16 >> 2) << 4))) =
                (bf16_t)acc[mi][ni][j];
          }
      __builtin_amdgcn_s_barrier();
      const int bb = rowbase >> 10;
      const int nb = rowbase & 1023;
#pragma unroll
      for (int it = 0; it < 16; ++it) {
        const int flat = it * 512 + tid;
        const int c = flat >> 5, r0 = (flat & 31) * 8;
        const int cc = (c >> 2) & 3;
        bf16x8 v = *(const bf16x8*)(epi + c * 512 + 2 * (r0 ^ (cc << 4)));
        const int f = colbase + c;
        const int h = (f >> 6) & 15, e = f & 63;
        const size_t bh = (size_t)(bb * 16 + h);
        *(bf16x8*)(vto + (bh * 64 + e) * 1024 + nb + r0) = v;  // contiguous n
      }
    }
  } else {
    // proj: two 128-row f32 passes (128x256x4 = 131072 B each)
#pragma unroll
    for (int p = 0; p < 2; ++p) {
      if (p) __builtin_amdgcn_s_barrier();  // pass-0 readers done
      if (wm == p) {
#pragma unroll
        for (int mi = 0; mi < 8; ++mi)
#pragma unroll
          for (int ni = 0; ni < 4; ++ni)
#pragma unroll
            for (int j = 0; j < 4; ++j) {
              const int rl = mi * 16 + g * 4 + j;        // local row 0..127
              const int c = wn * 64 + ni * 16 + c16;
              *(float*)(epi + rl * 1024 + 4 * (c ^ (g << 4))) = acc[mi][ni][j];
            }
      }
      __builtin_amdgcn_s_barrier();
#pragma unroll
      for (int it = 0; it < 16; ++it) {
        const int flat = it * 512 + tid;
        const int rl = flat >> 6, c0 = (flat & 63) * 4;
        const int gr = (rl >> 2) & 3;
        float4 v = *(const float4*)(epi + rl * 1024 + 4 * (c0 ^ (gr << 4)));
        const int pr = rowbase + p * 128 + rl;
        const int orow = (pr & ~1023) + perm[pr];
        const int dt = 128 << ems[pr];
        const int col = colbase + c0;
        const float4 bia = *(const float4*)(bias + col);
        const bool keep = col < dt;  // dt multiple of 128; uniform over 4
        float4 o;
        o.x = keep ? v.x + bia.x : 0.f;
        o.y = keep ? v.y + bia.y : 0.f;
        o.z = keep ? v.z + bia.z : 0.f;
        o.w = keep ? v.w + bia.w : 0.f;
        *(float4*)(yout + (size_t)orow * 1024 + col) = o;
      }
    }
  }
#undef STAGE
#undef LDFRAG
}

// ----------------------------------------------------------- attention ----
// Runs entirely in permuted token space (softmax over a batch's keys is
// permutation-invariant; each output row is its own query's result).
// 8 waves x 32 q-rows = 256 q rows / block. KVBLK=64 double-buffered in LDS
// (K row-major [64key][64d], V^T [64d][64key], both XOR-swizzled).
// Swapped QK^T: S = mfma32(Kfrag, Qfrag) -> lane holds P-row slice for
// q = lane&31 in registers; softmax fully in-register; P->bf16 via
// cvt_pk + permlane32_swap feeds PV's A operand directly.
__global__ __launch_bounds__(512, 2) void attn256(
    const bf16_t* __restrict__ Q, const bf16_t* __restrict__ Kb,
    const bf16_t* __restrict__ VT, bf16_t* __restrict__ X) {
  __shared__ bf16_t Klds[2][4096];
  __shared__ bf16_t Vlds[2][4096];
  const int tid = threadIdx.x;
  const int w = tid >> 6, lane = tid & 63;
  const int k32 = lane & 31, q5 = lane >> 5;
  const int bh = blockIdx.y;
  const int qbase = blockIdx.x * 256 + w * 32;

  const bf16_t* Qbh = Q + (size_t)bh * 65536;
  const bf16_t* Kbh = Kb + (size_t)bh * 65536;
  const bf16_t* Vbh = VT + (size_t)bh * 65536;

  const int trow = tid >> 3;
  const int tslot = (tid & 7) ^ (trow & 7);
  const bf16_t* kg = Kbh + (size_t)trow * 64 + tslot * 8;
  const bf16_t* vg = Vbh + (size_t)trow * 1024 + tslot * 8;

  bf16x8 qf[4];
#pragma unroll
  for (int kc = 0; kc < 4; ++kc)
    qf[kc] = *(const bf16x8*)(Qbh + (size_t)(qbase + k32) * 64 + kc * 16 + q5 * 8);
  asm volatile("" ::"v"(qf[0]), "v"(qf[1]), "v"(qf[2]), "v"(qf[3]));

  const int rbase = k32 * 128 + q5 * 16;
  const int rswz = (k32 & 7) << 4;

  f32x16 O0 = {}, O1 = {};
  float m = -3.0e38f, lsum = 0.f;

  GLOAD_LDS16(kg, (bf16_t*)Klds[0] + tid * 8);
  GLOAD_LDS16(vg, (bf16_t*)Vlds[0] + tid * 8);

  for (int step = 0; step < 16; ++step) {
    const int buf = step & 1;
    if (step < 15) {
      GLOAD_LDS16(kg + (step + 1) * 4096, (bf16_t*)Klds[buf ^ 1] + tid * 8);
      GLOAD_LDS16(vg + (step + 1) * 64, (bf16_t*)Vlds[buf ^ 1] + tid * 8);
      asm volatile("s_waitcnt vmcnt(2)" ::: "memory");
    } else {
      asm volatile("s_waitcnt vmcnt(0)" ::: "memory");
    }
    __builtin_amdgcn_s_barrier();

    const char* Kl = (const char*)Klds[buf];
    const char* Vl = (const char*)Vlds[buf];

    f32x16 S0 = {}, S1 = {};
#pragma unroll
    for (int kc = 0; kc < 4; ++kc) {
      const int off = (rbase + kc * 32) ^ rswz;
      bf16x8 kf0 = *(const bf16x8*)(Kl + off);
      bf16x8 kf1 = *(const bf16x8*)(Kl + off + 4096);
      S0 = MFMA32(kf0, qf[kc], S0);
      S1 = MFMA32(kf1, qf[kc], S1);
    }

    float pm = fmaxf(S0[0], S1[0]);
#pragma unroll
    for (int r = 1; r < 16; ++r) pm = fmaxf(pm, fmaxf(S0[r], S1[r]));
    pm = fmaxf(pm, __shfl_xor(pm, 32));
    if (__any(pm > m + 8.f)) {           // defer-max, THR=8 (log2 domain)
      const float mnew = fmaxf(m, pm);
      const float corr = __builtin_amdgcn_exp2f(m - mnew);
      m = mnew;
      lsum *= corr;
      const int ci = __builtin_bit_cast(int, corr);
#pragma unroll
      for (int r = 0; r < 16; ++r) {
        const int qsel = (r & 3) + 8 * (r >> 2) + 4 * q5;
        const float cr = __builtin_bit_cast(
            float, __builtin_amdgcn_ds_bpermute(qsel << 2, ci));
        O0[r] *= cr;
        O1[r] *= cr;
      }
    }
    float ps = 0.f;
#pragma unroll
    for (int r = 0; r < 16; ++r) {
      float p = __builtin_amdgcn_exp2f(S0[r] - m);
      ps += p; S0[r] = p;
      p = __builtin_amdgcn_exp2f(S1[r] - m);
      ps += p; S1[r] = p;
    }
    lsum += ps;

#define MAKE_PA(PV, B0, PA)                            \
  {                                                    \
    unsigned a_ = cvtpk(PV[B0 + 0], PV[B0 + 1]);       \
    unsigned b_ = cvtpk(PV[B0 + 2], PV[B0 + 3]);       \
    unsigned c_ = cvtpk(PV[B0 + 4], PV[B0 + 5]);       \
    unsigned d_ = cvtpk(PV[B0 + 6], PV[B0 + 7]);       \
    pl32swap(a_, c_);                                  \
    pl32swap(b_, d_);                                  \
    i32x4 wv_;                                         \
    wv_[0] = a_; wv_[1] = b_; wv_[2] = c_; wv_[3] = d_; \
    PA = __builtin_bit_cast(bf16x8, wv_);              \
  }
#define PV_STEP(PV, B0, KS)                                       \
  {                                                               \
    bf16x8 pa;                                                    \
    MAKE_PA(PV, B0, pa);                                          \
    const int voff = (rbase + (KS) * 32) ^ rswz;                  \
    bf16x8 vf0 = *(const bf16x8*)(Vl + voff);                     \
    bf16x8 vf1 = *(const bf16x8*)(Vl + voff + 4096);              \
    O0 = MFMA32(pa, vf0, O0);                                     \
    O1 = MFMA32(pa, vf1, O1);                                     \
  }
    PV_STEP(S0, 0, 0)
    PV_STEP(S0, 8, 1)
    PV_STEP(S1, 0, 2)
    PV_STEP(S1, 8, 3)

    __builtin_amdgcn_s_barrier();
  }

  lsum += __shfl_xor(lsum, 32);
  const float rinv = 1.f / lsum;
  const int ri = __builtin_bit_cast(int, rinv);
  const int bb = bh >> 4, h = bh & 15;
  bf16_t* Xb = X + (size_t)bb * 1024 * 1024 + h * 64;
#pragma unroll
  for (int r = 0; r < 16; ++r) {
    const int qsel = (r & 3) + 8 * (r >> 2) + 4 * q5;
    const float rv = __builtin_bit_cast(
        float, __builtin_amdgcn_ds_bpermute(qsel << 2, ri));
    const size_t rowoff = (size_t)(qbase + qsel) * 1024;
    Xb[rowoff + k32] = (bf16_t)(O0[r] * rv);
    Xb[rowoff + 32 + k32] = (bf16_t)(O1[r] * rv);
  }
}

// --------------------------------------------------------------- launch ----
extern "C" void kernel_launch(void* const* d_in, const int* in_sizes, int n_in,
                              void* d_out, int out_size, void* d_ws,
                              size_t ws_size, hipStream_t stream) {
  const float* x = (const float*)d_in[0];
  const int* em = (const int*)d_in[1];
  const float* qkvw = (const float*)d_in[2];
  const float* projw = (const float*)d_in[3];
  const float* projb = (const float*)d_in[4];
  float* out = (float*)d_out;

  char* ws = (char*)d_ws;
  size_t off = 0;
  bf16_t* xin = (bf16_t*)(ws + off); off += (size_t)16384 * 1024 * 2;  // reused as Xattn
  bf16_t* wq  = (bf16_t*)(ws + off); off += (size_t)3072 * 1024 * 2;
  bf16_t* wp  = (bf16_t*)(ws + off); off += (size_t)1024 * 1024 * 2;
  bf16_t* Qb  = (bf16_t*)(ws + off); off += (size_t)256 * 1024 * 64 * 2;
  bf16_t* Kb  = (bf16_t*)(ws + off); off += (size_t)256 * 1024 * 64 * 2;
  bf16_t* VTb = (bf16_t*)(ws + off); off += (size_t)256 * 64 * 1024 * 2;
  int* perm   = (int*)(ws + off); off += 16384 * 4;   // perm[b*1024+np] = n
  int* ems    = (int*)(ws + off); off += 16384 * 4;   // expert of sorted slot

  // per-batch counting sort (deterministic bucket structure)
  sort_batch<<<16, 256, 0, stream>>>(em, perm, ems);

  // gather tokens into permuted order + mask + bf16
  prep_tokens<<<16384, 256, 0, stream>>>(x, perm, ems, xin);
  conv_w<<<3072, 256, 0, stream>>>(qkvw, wq);
  conv_w<<<1024, 256, 0, stream>>>(projw, wp);

  // QKV: M=16384 (permuted space, nested-K), N=3072 -> 64x12 blocks
  gemm256<0><<<768, 512, 0, stream>>>(
      xin, wq, 1024, perm, ems, Qb, Kb, VTb, nullptr, nullptr);

  // attention in permuted space: 4 q-tiles x 256 (b,h); X -> xin region
  attn256<<<dim3(4, 256), 512, 0, stream>>>(Qb, Kb, VTb, xin);

  // proj: M=16384 (permuted), N=1024, masked-block skip, staged epilogue
  gemm256<1><<<256, 512, 0, stream>>>(
      xin, wp, 1024, perm, ems, nullptr, nullptr, nullptr, out, projb);
}

// Round 12
// 265.312 us; speedup vs baseline: 4.5400x; 1.0250x over previous
//
#include <hip/hip_runtime.h>
#include <hip/hip_bf16.h>

// NestedAttention: B=16,N=1024,D=1024,E=4,H=16,hd=64
// bf16 MFMA pipeline with fp32 accumulate.
// R12: attention overhaul — bh-major grid (same-bh q-tile blocks share an
// XCD L2 -> K/V fetched once), KVBLK=128 (half the barriers/waits per key),
// LDS-staged coalesced X epilogue (4 dwordx4/thread vs 32 scalar shorts).
// GEMMs = R11 (2-phase 256^2 + LDS-staged epilogues). Per-batch expert
// sort; permuted-space pipeline; nested-K QKV; masked-block-skip proj.

typedef __bf16 bf16_t;
typedef __bf16 bf16x8 __attribute__((ext_vector_type(8)));
typedef __bf16 bf16x4 __attribute__((ext_vector_type(4)));
typedef float f32x4 __attribute__((ext_vector_type(4)));
typedef float f32x16 __attribute__((ext_vector_type(16)));
typedef int i32x4 __attribute__((ext_vector_type(4)));

typedef __attribute__((address_space(1))) void gvoid;
typedef __attribute__((address_space(3))) void lvoid;

#define MFMA16(a, b, c) __builtin_amdgcn_mfma_f32_16x16x32_bf16((a), (b), (c), 0, 0, 0)
#define MFMA32(a, b, c) __builtin_amdgcn_mfma_f32_32x32x16_bf16((a), (b), (c), 0, 0, 0)
#define GLOAD_LDS16(gsrc, ldst) \
  __builtin_amdgcn_global_load_lds((gvoid*)(gsrc), (lvoid*)(ldst), 16, 0, 0)

// softmax scale 1/sqrt(64) folded with log2(e) into Q at QKV epilogue
#define QSCALE 0.18033688f

__device__ __forceinline__ unsigned cvtpk(float lo, float hi) {
  unsigned r;
  asm("v_cvt_pk_bf16_f32 %0, %1, %2" : "=v"(r) : "v"(lo), "v"(hi));
  return r;
}
__device__ __forceinline__ void pl32swap(unsigned& x, unsigned& y) {
  asm("v_permlane32_swap_b32 %0, %1" : "+v"(x), "+v"(y));
}

// ------------------------------------------------------------- sorting ----
// Per-batch counting sort (16 batches x 1024 tokens) into ascending-expert
// order. perm[b*1024+np] = original n; ems[b*1024+np] = expert. Bucket
// boundaries deterministic; within-bucket order race-dependent but every
// output row depends only on its own token -> bit-identical outputs.
__global__ __launch_bounds__(256) void sort_batch(
    const int* __restrict__ em, int* __restrict__ perm, int* __restrict__ ems) {
  __shared__ int cnt[4], base[4], cur[4];
  const int b = blockIdx.x, t = threadIdx.x;
  if (t < 4) cnt[t] = 0;
  __syncthreads();
  int e[4];
#pragma unroll
  for (int i = 0; i < 4; ++i) {
    e[i] = em[b * 1024 + t * 4 + i];
    atomicAdd(&cnt[e[i]], 1);
  }
  __syncthreads();
  if (t == 0) {
    base[0] = 0; base[1] = cnt[0];
    base[2] = cnt[0] + cnt[1]; base[3] = cnt[0] + cnt[1] + cnt[2];
    cur[0] = cur[1] = cur[2] = cur[3] = 0;
  }
  __syncthreads();
#pragma unroll
  for (int i = 0; i < 4; ++i) {
    const int pos = base[e[i]] + atomicAdd(&cur[e[i]], 1);
    perm[b * 1024 + pos] = t * 4 + i;
    ems[b * 1024 + pos] = e[i];
  }
}

// ---------------------------------------------------------------- prep ----
__global__ __launch_bounds__(256) void prep_tokens(
    const float* __restrict__ x, const int* __restrict__ perm,
    const int* __restrict__ ems, bf16_t* __restrict__ xq) {
  const int prow = blockIdx.x;                // permuted row 0..16383
  const int orig = (prow & ~1023) + perm[prow];
  const int dt = 128 << ems[prow];            // token's nested dim
  const int d = threadIdx.x * 4;
  float4 v = ((const float4*)(x + (size_t)orig * 1024))[threadIdx.x];
  const bool keep = d < dt;                   // dt multiple of 128 -> uniform per 4
  bf16x4 o;
  o[0] = (bf16_t)(keep ? v.x : 0.f);
  o[1] = (bf16_t)(keep ? v.y : 0.f);
  o[2] = (bf16_t)(keep ? v.z : 0.f);
  o[3] = (bf16_t)(keep ? v.w : 0.f);
  *((bf16x4*)(xq + (size_t)prow * 1024 + d)) = o;
}

__global__ __launch_bounds__(256) void conv_w(
    const float* __restrict__ s, bf16_t* __restrict__ dvec) {
  const int i = blockIdx.x * 256 + threadIdx.x;  // grid sized exactly, no guard
  float4 v = ((const float4*)s)[i];
  bf16x4 o;
  o[0] = (bf16_t)v.x; o[1] = (bf16_t)v.y; o[2] = (bf16_t)v.z; o[3] = (bf16_t)v.w;
  ((bf16x4*)dvec)[i] = o;
}

// ---------------------------------------------------------------- GEMM ----
// C[m,f] = sum_k A[m,k] * Bw[f,k]  ("B^T" GEMM), permuted-space rows.
// 256x256 tile, BK=64, 8 waves (2Mx4N), 2-phase K-loop (stage next tile
// first, compute, single vmcnt(0)+barrier per tile), T2 chunk-swizzle.
// Epilogues stage the C-tile into the now-dead 128KB LDS (XOR-swizzled)
// and emit only dwordx4 coalesced global stores.
template <int EPI>
__global__ __launch_bounds__(512, 2) void gemm256(
    const bf16_t* __restrict__ A, const bf16_t* __restrict__ Bw, int K,
    const int* __restrict__ perm, const int* __restrict__ ems,
    bf16_t* __restrict__ qo, bf16_t* __restrict__ ko, bf16_t* __restrict__ vto,
    float* __restrict__ yout, const float* __restrict__ bias) {
  __shared__ bf16_t lds[2][32768];  // K-loop dbuf; reused as 128KB epi stage
  const int tid = threadIdx.x;
  const int lane = tid & 63, w = tid >> 6;
  const int wm = w >> 2, wn = w & 3;
  const int g = lane >> 4, c16 = lane & 15;

  const int bid = blockIdx.x;
  const int rowbase = (bid & 63) * 256;   // row-blocks cycle fastest (balance)
  const int colbase = (bid >> 6) * 256;

  const int dtmax = 128 << ems[rowbase + 255];

  if constexpr (EPI == 1) {
    if (colbase >= dtmax) {  // whole block masked -> write zero rows, done
      const float4 z = make_float4(0.f, 0.f, 0.f, 0.f);
#pragma unroll
      for (int i = 0; i < 32; ++i) {
        const int idx = i * 512 + tid;
        const int r = idx >> 6, c4 = idx & 63;
        const int orow = ((rowbase + r) & ~1023) + perm[rowbase + r];
        ((float4*)(yout + (size_t)orow * 1024 + colbase))[c4] = z;
      }
      return;
    }
  }

  const int NT = (EPI == 0) ? (dtmax >> 6) : (K >> 6);

  const int trow = tid >> 3;
  const int scol = (((tid & 7) ^ (trow & 7)) << 3);
  const bf16_t* pa = A + (size_t)(rowbase + trow) * K + scol;
  const bf16_t* pb = Bw + (size_t)(colbase + trow) * K + scol;

#define STAGE(j, koff, dst)                                       \
  GLOAD_LDS16(((j) < 4 ? pa + (size_t)((j) * 64) * K              \
                       : pb + (size_t)(((j) - 4) * 64) * K) +     \
                  (koff),                                         \
              (dst) + ((j) * 512 + tid) * 8)

#define LDFRAG(base, R, kk)            \
  (*(const bf16x8*)((base) + (size_t)(R) * 64 + \
                    (((((kk) << 2) + g) ^ (c16 & 7)) << 3)))

  f32x4 acc[8][4] = {};

  // prologue: stage K-tile 0, drain, publish
#pragma unroll
  for (int j = 0; j < 8; ++j) STAGE(j, 0, (bf16_t*)lds[0]);
  asm volatile("s_waitcnt vmcnt(0)" ::: "memory");
  __builtin_amdgcn_s_barrier();

  for (int t = 0; t < NT; ++t) {
    const bf16_t* Lb = lds[t & 1];
    const bf16_t* LbB = Lb + 16384;
    const bool pf = (t + 1) < NT;

    if (pf) {  // issue next-tile staging FIRST (lands under this compute)
      bf16_t* Sd = (bf16_t*)lds[(t + 1) & 1];
      const int koff = (t + 1) << 6;
#pragma unroll
      for (int j = 0; j < 8; ++j) STAGE(j, koff, Sd);
    }

    bf16x8 af[4][2], af2[4][2], b0[2][2], b1[2][2];
#pragma unroll
    for (int mi = 0; mi < 4; ++mi)
#pragma unroll
      for (int kk = 0; kk < 2; ++kk)
        af[mi][kk] = LDFRAG(Lb, wm * 128 + mi * 16 + c16, kk);
#pragma unroll
    for (int ni = 0; ni < 2; ++ni)
#pragma unroll
      for (int kk = 0; kk < 2; ++kk)
        b0[ni][kk] = LDFRAG(LbB, wn * 64 + ni * 16 + c16, kk);
#pragma unroll
    for (int mi = 0; mi < 4; ++mi)
#pragma unroll
      for (int ni = 0; ni < 2; ++ni)
#pragma unroll
        for (int kk = 0; kk < 2; ++kk)
          acc[mi][ni] = MFMA16(af[mi][kk], b0[ni][kk], acc[mi][ni]);

#pragma unroll
    for (int ni = 0; ni < 2; ++ni)
#pragma unroll
      for (int kk = 0; kk < 2; ++kk)
        b1[ni][kk] = LDFRAG(LbB, wn * 64 + (ni + 2) * 16 + c16, kk);
#pragma unroll
    for (int mi = 0; mi < 4; ++mi)
#pragma unroll
      for (int ni = 0; ni < 2; ++ni)
#pragma unroll
        for (int kk = 0; kk < 2; ++kk)
          acc[mi][ni + 2] = MFMA16(af[mi][kk], b1[ni][kk], acc[mi][ni + 2]);

#pragma unroll
    for (int mi = 0; mi < 4; ++mi)
#pragma unroll
      for (int kk = 0; kk < 2; ++kk)
        af2[mi][kk] = LDFRAG(Lb, wm * 128 + (mi + 4) * 16 + c16, kk);
#pragma unroll
    for (int mi = 0; mi < 4; ++mi)
#pragma unroll
      for (int ni = 0; ni < 2; ++ni)
#pragma unroll
        for (int kk = 0; kk < 2; ++kk)
          acc[mi + 4][ni] = MFMA16(af2[mi][kk], b0[ni][kk], acc[mi + 4][ni]);

#pragma unroll
    for (int mi = 0; mi < 4; ++mi)
#pragma unroll
      for (int ni = 0; ni < 2; ++ni)
#pragma unroll
        for (int kk = 0; kk < 2; ++kk)
          acc[mi + 4][ni + 2] = MFMA16(af2[mi][kk], b1[ni][kk], acc[mi + 4][ni + 2]);

    if (pf) asm volatile("s_waitcnt vmcnt(0)" ::: "memory");
    __builtin_amdgcn_s_barrier();  // also frees LDS for the epilogue
  }

  // ---- epilogue: LDS-staged, coalesced dwordx4 stores ----
  // C/D frag layout: col = lane&15, row = (lane>>4)*4 + reg [m89/m91].
  char* epi = (char*)lds;  // 131072 B = exactly one 256x256 bf16 tile
  if constexpr (EPI == 0) {
    const int s = colbase >> 10;          // 0=q, 1=k, 2=v (uniform per block)
    const float qs = (s == 0) ? QSCALE : 1.0f;
    if (s < 2) {
      // stage [r][c], col XOR'd by g=(r>>2)&3 (write 2-way = free)
#pragma unroll
      for (int mi = 0; mi < 8; ++mi)
#pragma unroll
        for (int ni = 0; ni < 4; ++ni)
#pragma unroll
          for (int j = 0; j < 4; ++j) {
            const int r = wm * 128 + mi * 16 + g * 4 + j;
            const int c = wn * 64 + ni * 16 + c16;
            *(bf16_t*)(epi + r * 512 + 2 * (c ^ (g << 4))) =
                (bf16_t)(acc[mi][ni][j] * qs);
          }
      __builtin_amdgcn_s_barrier();
      bf16_t* const dstbase = (s == 0) ? qo : ko;
#pragma unroll
      for (int it = 0; it < 16; ++it) {
        const int flat = it * 512 + tid;
        const int r = flat >> 5, c0 = (flat & 31) * 8;
        const int gr = (r >> 2) & 3;
        bf16x8 v = *(const bf16x8*)(epi + r * 512 + 2 * (c0 ^ (gr << 4)));
        const int prow = rowbase + r;
        const int bb = prow >> 10, n = prow & 1023;
        const int f = colbase + c0;
        const int h = (f >> 6) & 15, e = f & 63;
        const size_t bh = (size_t)(bb * 16 + h);
        *(bf16x8*)(dstbase + (bh * 1024 + n) * 64 + e) = v;
      }
    } else {
      // stage transposed [c][r], row XOR'd by (c16>>2)&3 (write 4-way)
#pragma unroll
      for (int mi = 0; mi < 8; ++mi)
#pragma unroll
        for (int ni = 0; ni < 4; ++ni)
#pragma unroll
          for (int j = 0; j < 4; ++j) {
            const int r = wm * 128 + mi * 16 + g * 4 + j;
            const int c = wn * 64 + ni * 16 + c16;
            *(bf16_t*)(epi + c * 512 + 2 * (r ^ ((c16 >> 2) << 4))) =
                (bf16_t)acc[mi][ni][j];
          }
      __builtin_amdgcn_s_barrier();
      const int bb = rowbase >> 10;
      const int nb = rowbase & 1023;
#pragma unroll
      for (int it = 0; it < 16; ++it) {
        const int flat = it * 512 + tid;
        const int c = flat >> 5, r0 = (flat & 31) * 8;
        const int cc = (c >> 2) & 3;
        bf16x8 v = *(const bf16x8*)(epi + c * 512 + 2 * (r0 ^ (cc << 4)));
        const int f = colbase + c;
        const int h = (f >> 6) & 15, e = f & 63;
        const size_t bh = (size_t)(bb * 16 + h);
        *(bf16x8*)(vto + (bh * 64 + e) * 1024 + nb + r0) = v;  // contiguous n
      }
    }
  } else {
    // proj: two 128-row f32 passes (128x256x4 = 131072 B each)
#pragma unroll
    for (int p = 0; p < 2; ++p) {
      if (p) __builtin_amdgcn_s_barrier();  // pass-0 readers done
      if (wm == p) {
#pragma unroll
        for (int mi = 0; mi < 8; ++mi)
#pragma unroll
          for (int ni = 0; ni < 4; ++ni)
#pragma unroll
            for (int j = 0; j < 4; ++j) {
              const int rl = mi * 16 + g * 4 + j;        // local row 0..127
              const int c = wn * 64 + ni * 16 + c16;
              *(float*)(epi + rl * 1024 + 4 * (c ^ (g << 4))) = acc[mi][ni][j];
            }
      }
      __builtin_amdgcn_s_barrier();
#pragma unroll
      for (int it = 0; it < 16; ++it) {
        const int flat = it * 512 + tid;
        const int rl = flat >> 6, c0 = (flat & 63) * 4;
        const int gr = (rl >> 2) & 3;
        float4 v = *(const float4*)(epi + rl * 1024 + 4 * (c0 ^ (gr << 4)));
        const int pr = rowbase + p * 128 + rl;
        const int orow = (pr & ~1023) + perm[pr];
        const int dt = 128 << ems[pr];
        const int col = colbase + c0;
        const float4 bia = *(const float4*)(bias + col);
        const bool keep = col < dt;  // dt multiple of 128; uniform over 4
        float4 o;
        o.x = keep ? v.x + bia.x : 0.f;
        o.y = keep ? v.y + bia.y : 0.f;
        o.z = keep ? v.z + bia.z : 0.f;
        o.w = keep ? v.w + bia.w : 0.f;
        *(float4*)(yout + (size_t)orow * 1024 + col) = o;
      }
    }
  }
#undef STAGE
#undef LDFRAG
}

// ----------------------------------------------------------- attention ----
// Permuted token space. Grid dim3(256,4): x = bh (same-bh q-tile blocks land
// on the same XCD: linear id = bh + 256*qt, id%8 = bh%8 -> K/V L2-shared),
// y = q-tile. 8 waves x 32 q-rows. KVBLK=128 double-buffered (K [128][64],
// V^T [64][128], XOR-swizzled; 64KB LDS); 2 barriers + 4 gloads per 128
// keys. Swapped QK^T (mfma32(K,Q)) -> lane-local softmax per 64-key half;
// P->bf16 via cvt_pk+permlane32_swap. X epilogue staged through LDS ->
// dwordx4 stores.
__global__ __launch_bounds__(512, 2) void attn256(
    const bf16_t* __restrict__ Q, const bf16_t* __restrict__ Kb,
    const bf16_t* __restrict__ VT, bf16_t* __restrict__ X) {
  __shared__ bf16_t Klds[2][8192];  // [128 keys][64 d], 16KB per buf
  __shared__ bf16_t Vlds[2][8192];  // [64 d][128 keys], 16KB per buf
  const int tid = threadIdx.x;
  const int w = tid >> 6, lane = tid & 63;
  const int k32 = lane & 31, q5 = lane >> 5;
  const int bh = blockIdx.x;
  const int qbase0 = blockIdx.y * 256;
  const int qbase = qbase0 + w * 32;

  const bf16_t* Qbh = Q + (size_t)bh * 65536;
  const bf16_t* Kbh = Kb + (size_t)bh * 65536;
  const bf16_t* Vbh = VT + (size_t)bh * 65536;

  // staging (rule #21: linear LDS dest, inverse-swizzled global source)
  const int ktrow = tid >> 3;                       // key row 0..63 per gload
  const int ktslot = (tid & 7) ^ (ktrow & 7);       // 8x16B slots per 128B row
  const bf16_t* kg = Kbh + (size_t)ktrow * 64 + ktslot * 8;
  const int vtrow = tid >> 4;                       // d row 0..31 per gload
  const int vtslot = (tid & 15) ^ (vtrow & 15);     // 16x16B slots per 256B row
  const bf16_t* vg = Vbh + (size_t)vtrow * 1024 + vtslot * 8;

#define STAGE_KV(b, kt)                                              \
  {                                                                  \
    GLOAD_LDS16(kg + (size_t)(kt) * 64, (bf16_t*)Klds[b] + tid * 8); \
    GLOAD_LDS16(kg + (size_t)(kt) * 64 + 4096,                      \
                (bf16_t*)Klds[b] + 4096 + tid * 8);                  \
    GLOAD_LDS16(vg + (kt), (bf16_t*)Vlds[b] + tid * 8);              \
    GLOAD_LDS16(vg + (kt) + 32768, (bf16_t*)Vlds[b] + 4096 + tid * 8); \
  }

  bf16x8 qf[4];
#pragma unroll
  for (int kc = 0; kc < 4; ++kc)
    qf[kc] = *(const bf16x8*)(Qbh + (size_t)(qbase + k32) * 64 + kc * 16 + q5 * 8);
  asm volatile("" ::"v"(qf[0]), "v"(qf[1]), "v"(qf[2]), "v"(qf[3]));

  const int rswz8 = (k32 & 7) << 4;    // K-read swizzle (128B rows)
  const int rswz16 = (k32 & 15) << 4;  // V-read swizzle (256B rows)

  f32x16 O0 = {}, O1 = {};
  float m = -3.0e38f, lsum = 0.f;

  STAGE_KV(0, 0);

  for (int step = 0; step < 8; ++step) {
    const int buf = step & 1;
    if (step < 7) {
      STAGE_KV(buf ^ 1, (step + 1) * 128);
      asm volatile("s_waitcnt vmcnt(4)" ::: "memory");
    } else {
      asm volatile("s_waitcnt vmcnt(0)" ::: "memory");
    }
    __builtin_amdgcn_s_barrier();

    const char* Vl = (const char*)Vlds[buf];

#pragma unroll
    for (int h = 0; h < 2; ++h) {   // two 64-key halves of the 128-key tile
      const char* Kl = (const char*)Klds[buf] + h * 8192;

      f32x16 S0 = {}, S1 = {};
#pragma unroll
      for (int kc = 0; kc < 4; ++kc) {
        const int off = k32 * 128 + ((q5 * 16 + kc * 32) ^ rswz8);
        bf16x8 kf0 = *(const bf16x8*)(Kl + off);
        bf16x8 kf1 = *(const bf16x8*)(Kl + off + 4096);
        S0 = MFMA32(kf0, qf[kc], S0);
        S1 = MFMA32(kf1, qf[kc], S1);
      }

      float pm = fmaxf(S0[0], S1[0]);
#pragma unroll
      for (int r = 1; r < 16; ++r) pm = fmaxf(fmaxf(S0[r], S1[r]), pm);
      pm = fmaxf(pm, __shfl_xor(pm, 32));
      if (__any(pm > m + 8.f)) {         // defer-max, THR=8 (log2 domain)
        const float mnew = fmaxf(m, pm);
        const float corr = __builtin_amdgcn_exp2f(m - mnew);
        m = mnew;
        lsum *= corr;
        const int ci = __builtin_bit_cast(int, corr);
#pragma unroll
        for (int r = 0; r < 16; ++r) {
          const int qsel = (r & 3) + 8 * (r >> 2) + 4 * q5;
          const float cr = __builtin_bit_cast(
              float, __builtin_amdgcn_ds_bpermute(qsel << 2, ci));
          O0[r] *= cr;
          O1[r] *= cr;
        }
      }
      float ps = 0.f;
#pragma unroll
      for (int r = 0; r < 16; ++r) {
        float p = __builtin_amdgcn_exp2f(S0[r] - m);
        ps += p; S0[r] = p;
        p = __builtin_amdgcn_exp2f(S1[r] - m);
        ps += p; S1[r] = p;
      }
      lsum += ps;

#define MAKE_PA(PV, B0, PA)                            \
  {                                                    \
    unsigned a_ = cvtpk(PV[B0 + 0], PV[B0 + 1]);       \
    unsigned b_ = cvtpk(PV[B0 + 2], PV[B0 + 3]);       \
    unsigned c_ = cvtpk(PV[B0 + 4], PV[B0 + 5]);       \
    unsigned d_ = cvtpk(PV[B0 + 6], PV[B0 + 7]);       \
    pl32swap(a_, c_);                                  \
    pl32swap(b_, d_);                                  \
    i32x4 wv_;                                         \
    wv_[0] = a_; wv_[1] = b_; wv_[2] = c_; wv_[3] = d_; \
    PA = __builtin_bit_cast(bf16x8, wv_);              \
  }
#define PV_STEP(PV, B0, KS)                                         \
  {                                                                 \
    bf16x8 pa;                                                      \
    MAKE_PA(PV, B0, pa);                                            \
    const int voff = k32 * 256 + ((q5 * 16 + (KS) * 32) ^ rswz16);  \
    bf16x8 vf0 = *(const bf16x8*)(Vl + voff);                       \
    bf16x8 vf1 = *(const bf16x8*)(Vl + voff + 8192);                \
    O0 = MFMA32(pa, vf0, O0);                                       \
    O1 = MFMA32(pa, vf1, O1);                                       \
  }
      PV_STEP(S0, 0, h * 4 + 0)
      PV_STEP(S0, 8, h * 4 + 1)
      PV_STEP(S1, 0, h * 4 + 2)
      PV_STEP(S1, 8, h * 4 + 3)
    }

    __builtin_amdgcn_s_barrier();
  }

  // ---- epilogue: normalize, stage X-tile (256x64 bf16 = 32KB) into the
  // dead K region, then coalesced dwordx4 stores.
  lsum += __shfl_xor(lsum, 32);
  const float rinv = 1.f / lsum;
  const int ri = __builtin_bit_cast(int, rinv);
  char* Xs = (char*)Klds;  // 32 KB
#pragma unroll
  for (int r = 0; r < 16; ++r) {
    const int qsel = (r & 3) + 8 * (r >> 2) + 4 * q5;
    const float rv = __builtin_bit_cast(
        float, __builtin_amdgcn_ds_bpermute(qsel << 2, ri));
    const int row = w * 32 + qsel;          // local row 0..255
    const int msk = (row & 7) << 4;
    *(bf16_t*)(Xs + row * 128 + ((2 * k32) ^ msk)) = (bf16_t)(O0[r] * rv);
    *(bf16_t*)(Xs + row * 128 + ((64 + 2 * k32) ^ msk)) = (bf16_t)(O1[r] * rv);
  }
  __builtin_amdgcn_s_barrier();
  const int bb = bh >> 4, h = bh & 15;
  bf16_t* Xb = X + (size_t)bb * 1024 * 1024 + h * 64;
#pragma unroll
  for (int it = 0; it < 4; ++it) {
    const int flat = it * 512 + tid;
    const int row = flat >> 3, ch = flat & 7;
    bf16x8 v = *(const bf16x8*)(Xs + row * 128 + ((ch * 16) ^ ((row & 7) << 4)));
    *(bf16x8*)(Xb + (size_t)(qbase0 + row) * 1024 + ch * 8) = v;
  }
#undef STAGE_KV
#undef MAKE_PA
#undef PV_STEP
}

// --------------------------------------------------------------- launch ----
extern "C" void kernel_launch(void* const* d_in, const int* in_sizes, int n_in,
                              void* d_out, int out_size, void* d_ws,
                              size_t ws_size, hipStream_t stream) {
  const float* x = (const float*)d_in[0];
  const int* em = (const int*)d_in[1];
  const float* qkvw = (const float*)d_in[2];
  const float* projw = (const float*)d_in[3];
  const float* projb = (const float*)d_in[4];
  float* out = (float*)d_out;

  char* ws = (char*)d_ws;
  size_t off = 0;
  bf16_t* xin = (bf16_t*)(ws + off); off += (size_t)16384 * 1024 * 2;  // reused as Xattn
  bf16_t* wq  = (bf16_t*)(ws + off); off += (size_t)3072 * 1024 * 2;
  bf16_t* wp  = (bf16_t*)(ws + off); off += (size_t)1024 * 1024 * 2;
  bf16_t* Qb  = (bf16_t*)(ws + off); off += (size_t)256 * 1024 * 64 * 2;
  bf16_t* Kb  = (bf16_t*)(ws + off); off += (size_t)256 * 1024 * 64 * 2;
  bf16_t* VTb = (bf16_t*)(ws + off); off += (size_t)256 * 64 * 1024 * 2;
  int* perm   = (int*)(ws + off); off += 16384 * 4;   // perm[b*1024+np] = n
  int* ems    = (int*)(ws + off); off += 16384 * 4;   // expert of sorted slot

  // per-batch counting sort (deterministic bucket structure)
  sort_batch<<<16, 256, 0, stream>>>(em, perm, ems);

  // gather tokens into permuted order + mask + bf16
  prep_tokens<<<16384, 256, 0, stream>>>(x, perm, ems, xin);
  conv_w<<<3072, 256, 0, stream>>>(qkvw, wq);
  conv_w<<<1024, 256, 0, stream>>>(projw, wp);

  // QKV: M=16384 (permuted space, nested-K), N=3072 -> 64x12 blocks
  gemm256<0><<<768, 512, 0, stream>>>(
      xin, wq, 1024, perm, ems, Qb, Kb, VTb, nullptr, nullptr);

  // attention in permuted space: bh-major grid (XCD L2 sharing of K/V)
  attn256<<<dim3(256, 4), 512, 0, stream>>>(Qb, Kb, VTb, xin);

  // proj: M=16384 (permuted), N=1024, masked-block skip, staged epilogue
  gemm256<1><<<256, 512, 0, stream>>>(
      xin, wp, 1024, perm, ems, nullptr, nullptr, nullptr, out, projb);
}